// Round 1
// baseline (4002.885 us; speedup 1.0000x reference)
//
#include <hip/hip_runtime.h>
#include <math.h>

// Swin stage: B=31 images, H=W=64 (4096 tokens), DIM=60, NH=6, HD=10, WS=8.
// Block 0: shift 0.  Block 1: shift 4.
// Activations layout: (31, 4096, 60) fp32.

#define NB   31
#define NTOK 4096
#define DIM  60
#define NHD  6
#define HDsz 10
#define QK_SCALE 0.31622776601683794f  // 10^-0.5

// ---------------- embed: (60,31,4096) -> (31,4096,60) ----------------
__global__ __launch_bounds__(256) void embed_t(const float* __restrict__ in,
                                               float* __restrict__ out)
{
    __shared__ float tile[64][61];
    int blk = blockIdx.x;
    int b  = blk >> 6;
    int t0 = (blk & 63) << 6;
    for (int idx = threadIdx.x; idx < 64 * DIM; idx += 256) {
        int d = idx >> 6, i = idx & 63;
        tile[i][d] = in[((size_t)d * NB + b) * NTOK + t0 + i];
    }
    __syncthreads();
    float* op = out + ((size_t)b * NTOK + t0) * DIM;
    for (int idx = threadIdx.x; idx < 64 * DIM; idx += 256) {
        int i = idx / DIM, d = idx - i * DIM;
        op[idx] = tile[i][d];
    }
}

// ---------------- unembed: (31,4096,60) -> (60,31,4096) ----------------
__global__ __launch_bounds__(256) void unembed_t(const float* __restrict__ in,
                                                 float* __restrict__ out)
{
    __shared__ float tile[64][61];
    int blk = blockIdx.x;
    int b  = blk >> 6;
    int t0 = (blk & 63) << 6;
    const float* ip = in + ((size_t)b * NTOK + t0) * DIM;
    for (int idx = threadIdx.x; idx < 64 * DIM; idx += 256) {
        int i = idx / DIM, d = idx - i * DIM;
        tile[i][d] = ip[idx];
    }
    __syncthreads();
    for (int idx = threadIdx.x; idx < 64 * DIM; idx += 256) {
        int d = idx >> 6, i = idx & 63;
        out[((size_t)d * NB + b) * NTOK + t0 + i] = tile[i][d];
    }
}

// ---------------- fused window attention ----------------
// One block per window (31*64 = 1984 blocks, 256 threads).
// LN1 -> qkv (per head) -> scores(+bias,+mask) -> softmax -> @V -> proj -> +residual
__global__ __launch_bounds__(256) void swin_attn(
    const float* __restrict__ xin_buf,   // (31,4096,60)
    float* __restrict__ xout_buf,        // (31,4096,60)
    const float* __restrict__ g1, const float* __restrict__ b1,
    const float* __restrict__ qkv_w,     // (180,60)
    const float* __restrict__ qkv_b,     // (180)
    const float* __restrict__ rpb,       // (225,6)
    const float* __restrict__ proj_w,    // (60,60)
    const float* __restrict__ proj_b,    // (60)
    int shift)
{
    __shared__ float xn[64][DIM];
    __shared__ float qh[64][HDsz];
    __shared__ float kh[64][HDsz];
    __shared__ float vh[64][HDsz];
    __shared__ float sc[64][64];
    __shared__ float oacc[64][DIM];

    const int tid = threadIdx.x;
    const int blk = blockIdx.x;
    const int b  = blk >> 6;      // image
    const int w  = blk & 63;      // window index (wy*8+wx)
    const int wy = w >> 3, wx = w & 7;

    const int tk = tid >> 2;      // token 0..63 inside window
    const int l4 = tid & 3;
    const int ty = tk >> 3, tx = tk & 7;
    // roll by -shift: window content comes from (pos+shift) mod 64
    const int hsrc = (wy * 8 + ty + shift) & 63;
    const int wsrc = (wx * 8 + tx + shift) & 63;
    const int tsrc = hsrc * 64 + wsrc;

    const float* xrow = xin_buf + ((size_t)b * NTOK + tsrc) * DIM;

    // ---- load + LayerNorm (4 threads per token, d = dd*4 + l4) ----
    float xr[15];
    float s = 0.f, s2 = 0.f;
#pragma unroll
    for (int dd = 0; dd < 15; ++dd) {
        float v = xrow[dd * 4 + l4];
        xr[dd] = v;
        s += v; s2 += v * v;
    }
    s  += __shfl_xor(s, 1);   s  += __shfl_xor(s, 2);
    s2 += __shfl_xor(s2, 1);  s2 += __shfl_xor(s2, 2);
    const float mu  = s * (1.f / 60.f);
    const float var = s2 * (1.f / 60.f) - mu * mu;
    const float rs  = rsqrtf(var + 1e-5f);
#pragma unroll
    for (int dd = 0; dd < 15; ++dd) {
        int d = dd * 4 + l4;
        xn[tk][d] = (xr[dd] - mu) * rs * g1[d] + b1[d];
    }
    __syncthreads();

    // ---- per-head attention ----
    for (int h = 0; h < NHD; ++h) {
        // q/k/v for this head: 3 * 64 * 10 = 1920 outputs
        for (int o = tid; o < 1920; o += 256) {
            int which = o / 640;
            int rem = o - which * 640;
            int t = rem / 10;
            int e = rem - t * 10;
            int j = which * 60 + h * 10 + e;
            const float* wr = qkv_w + j * 60;
            const float* xnr = &xn[t][0];
            float acc = qkv_b[j];
#pragma unroll
            for (int d = 0; d < 60; d += 4) {
                float4 xv = *(const float4*)(xnr + d);
                float4 wv = *(const float4*)(wr + d);
                acc += xv.x * wv.x + xv.y * wv.y + xv.z * wv.z + xv.w * wv.w;
            }
            if (which == 0)      qh[t][e] = acc * QK_SCALE;
            else if (which == 1) kh[t][e] = acc;
            else                 vh[t][e] = acc;
        }
        __syncthreads();

        // scores: 64x64, + rel-pos bias, + shift mask
        for (int o = tid; o < 4096; o += 256) {
            int i = o >> 6, j = o & 63;
            float acc = 0.f;
#pragma unroll
            for (int e = 0; e < HDsz; ++e) acc += qh[i][e] * kh[j][e];
            int iy = i >> 3, ix = i & 7, jy = j >> 3, jx = j & 7;
            int rel = (iy - jy + 7) * 15 + (ix - jx + 7);
            acc += rpb[rel * 6 + h];
            if (shift) {
                int him = wy * 8 + iy, wim = wx * 8 + ix;
                int hjm = wy * 8 + jy, wjm = wx * 8 + jx;
                int ri = (him < 56 ? 0 : (him < 60 ? 1 : 2)) * 3
                       + (wim < 56 ? 0 : (wim < 60 ? 1 : 2));
                int rj = (hjm < 56 ? 0 : (hjm < 60 ? 1 : 2)) * 3
                       + (wjm < 56 ? 0 : (wjm < 60 ? 1 : 2));
                if (ri != rj) acc -= 100.f;
            }
            sc[i][j] = acc;
        }
        __syncthreads();

        // softmax per row: 4 lanes per row
        {
            float vb[16];
            float m = -1e30f;
#pragma unroll
            for (int u = 0; u < 16; ++u) {
                float v = sc[tk][l4 + u * 4];
                vb[u] = v;
                m = fmaxf(m, v);
            }
            m = fmaxf(m, __shfl_xor(m, 1));
            m = fmaxf(m, __shfl_xor(m, 2));
            float ssum = 0.f;
#pragma unroll
            for (int u = 0; u < 16; ++u) {
                float e = __expf(vb[u] - m);
                vb[u] = e;
                ssum += e;
            }
            ssum += __shfl_xor(ssum, 1);
            ssum += __shfl_xor(ssum, 2);
            float inv = 1.f / ssum;
#pragma unroll
            for (int u = 0; u < 16; ++u) sc[tk][l4 + u * 4] = vb[u] * inv;
        }
        __syncthreads();

        // attn @ v: 64 x 10 outputs
        for (int o = tid; o < 640; o += 256) {
            int i = o / 10, e = o - (o / 10) * 10;
            float acc = 0.f;
#pragma unroll
            for (int j = 0; j < 64; ++j) acc += sc[i][j] * vh[j][e];
            oacc[i][h * 10 + e] = acc;
        }
        __syncthreads();
    }

    // ---- proj + residual + scatter ----
    float* orow = xout_buf + ((size_t)b * NTOK + tsrc) * DIM;
#pragma unroll
    for (int dd = 0; dd < 15; ++dd) {
        int d = dd * 4 + l4;
        const float* wr = proj_w + d * 60;
        float acc = proj_b[d];
#pragma unroll
        for (int c = 0; c < 60; c += 4) {
            float4 ov = *(const float4*)(&oacc[tk][c]);
            float4 wv = *(const float4*)(wr + c);
            acc += ov.x * wv.x + ov.y * wv.y + ov.z * wv.z + ov.w * wv.w;
        }
        orow[d] = xr[dd] + acc;
    }
}

// ---------------- fused MLP: LN2 + fc1 + GELU + fc2 + residual ----------------
// 64 tokens per block, 256 threads (4 per token).
__global__ __launch_bounds__(256) void swin_mlp(
    const float* __restrict__ xin_buf,
    float* __restrict__ xout_buf,
    const float* __restrict__ g2, const float* __restrict__ b2,
    const float* __restrict__ fc1_w,   // (240,60)
    const float* __restrict__ fc1_b,   // (240)
    const float* __restrict__ fc2_w,   // (60,240)
    const float* __restrict__ fc2_b)   // (60)
{
    __shared__ float xn[64][DIM];
    __shared__ float h1[64][240];

    const int tid = threadIdx.x;
    const int tk = tid >> 2;
    const int l4 = tid & 3;
    const size_t t = (size_t)blockIdx.x * 64 + tk;
    const float* xrow = xin_buf + t * DIM;

    float xr[15];
    float s = 0.f, s2 = 0.f;
#pragma unroll
    for (int dd = 0; dd < 15; ++dd) {
        float v = xrow[dd * 4 + l4];
        xr[dd] = v;
        s += v; s2 += v * v;
    }
    s  += __shfl_xor(s, 1);   s  += __shfl_xor(s, 2);
    s2 += __shfl_xor(s2, 1);  s2 += __shfl_xor(s2, 2);
    const float mu  = s * (1.f / 60.f);
    const float var = s2 * (1.f / 60.f) - mu * mu;
    const float rs  = rsqrtf(var + 1e-5f);
#pragma unroll
    for (int dd = 0; dd < 15; ++dd) {
        int d = dd * 4 + l4;
        xn[tk][d] = (xr[dd] - mu) * rs * g2[d] + b2[d];
    }
    __syncthreads();

    // fc1 + exact GELU: each thread 60 outputs (j = jj*4 + l4)
    for (int jj = 0; jj < 60; ++jj) {
        int j = jj * 4 + l4;
        const float* wr = fc1_w + j * 60;
        const float* xnr = &xn[tk][0];
        float acc = fc1_b[j];
#pragma unroll
        for (int d = 0; d < 60; d += 4) {
            float4 xv = *(const float4*)(xnr + d);
            float4 wv = *(const float4*)(wr + d);
            acc += xv.x * wv.x + xv.y * wv.y + xv.z * wv.z + xv.w * wv.w;
        }
        // exact GELU
        h1[tk][j] = 0.5f * acc * (1.f + erff(acc * 0.70710678118654752f));
    }
    __syncthreads();

    // fc2 + residual: each thread 15 outputs (d = dd*4 + l4)
    float* orow = xout_buf + t * DIM;
#pragma unroll
    for (int dd = 0; dd < 15; ++dd) {
        int d = dd * 4 + l4;
        const float* wr = fc2_w + d * 240;
        const float* hr = &h1[tk][0];
        float acc = fc2_b[d];
#pragma unroll
        for (int c = 0; c < 240; c += 4) {
            float4 hv = *(const float4*)(hr + c);
            float4 wv = *(const float4*)(wr + c);
            acc += hv.x * wv.x + hv.y * wv.y + hv.z * wv.z + hv.w * wv.w;
        }
        orow[d] = xr[dd] + acc;
    }
}

extern "C" void kernel_launch(void* const* d_in, const int* in_sizes, int n_in,
                              void* d_out, int out_size, void* d_ws, size_t ws_size,
                              hipStream_t stream)
{
    const float* x       = (const float*)d_in[0];
    const float* norm1_g = (const float*)d_in[1];
    const float* norm1_b = (const float*)d_in[2];
    const float* qkv_w   = (const float*)d_in[3];
    const float* qkv_b   = (const float*)d_in[4];
    const float* rpb     = (const float*)d_in[5];
    const float* proj_w  = (const float*)d_in[6];
    const float* proj_b  = (const float*)d_in[7];
    const float* norm2_g = (const float*)d_in[8];
    const float* norm2_b = (const float*)d_in[9];
    const float* fc1_w   = (const float*)d_in[10];
    const float* fc1_b   = (const float*)d_in[11];
    const float* fc2_w   = (const float*)d_in[12];
    const float* fc2_b   = (const float*)d_in[13];

    float* ws  = (float*)d_ws;   // (31,4096,60) activations, 30.5 MB
    float* out = (float*)d_out;  // same element count; used as ping-pong buffer

    const int NWG = NB * 64;  // 1984
    dim3 grid(NWG), block(256);

    // embed: x -> ws
    embed_t<<<grid, block, 0, stream>>>(x, ws);

    for (int i = 0; i < 2; ++i) {
        int shift = (i == 0) ? 0 : 4;
        // attention: ws -> out
        swin_attn<<<grid, block, 0, stream>>>(
            ws, out,
            norm1_g + i * 60, norm1_b + i * 60,
            qkv_w + i * 180 * 60, qkv_b + i * 180,
            rpb + i * 225 * 6,
            proj_w + i * 60 * 60, proj_b + i * 60,
            shift);
        // MLP: out -> ws
        swin_mlp<<<grid, block, 0, stream>>>(
            out, ws,
            norm2_g + i * 60, norm2_b + i * 60,
            fc1_w + i * 240 * 60, fc1_b + i * 240,
            fc2_w + i * 60 * 240, fc2_b + i * 60);
    }

    // unembed: ws -> d_out
    unembed_t<<<grid, block, 0, stream>>>(ws, out);
}

// Round 2
// 1045.121 us; speedup vs baseline: 3.8301x; 3.8301x over previous
//
#include <hip/hip_runtime.h>
#include <math.h>

// Swin stage: B=31 images, H=W=64 (4096 tokens), DIM=60, NH=6, HD=10, WS=8.
// All GEMM-shaped work on bf16 MFMA 16x16x32.
// Activations layout: (31, 4096, 60) fp32, ping-pong between d_ws and d_out.

#define NB   31
#define NTOK 4096
#define DIM  60
#define QK_SCALE 0.31622776601683794f  // 10^-0.5

typedef __attribute__((ext_vector_type(8))) short bf16x8;
typedef __attribute__((ext_vector_type(4))) float f32x4;

__device__ __forceinline__ short f2b(float f) {
    union { float f; unsigned u; } v; v.f = f;
    unsigned r = (v.u + 0x7FFFu + ((v.u >> 16) & 1u)) >> 16;  // RNE
    return (short)r;
}

#define MFMA16(a, b, c) __builtin_amdgcn_mfma_f32_16x16x32_bf16(a, b, c, 0, 0, 0)

// ---------------- embed: (60,31,4096) -> (31,4096,60) ----------------
__global__ __launch_bounds__(256) void embed_t(const float* __restrict__ in,
                                               float* __restrict__ out)
{
    __shared__ float tile[64][61];
    int blk = blockIdx.x;
    int b  = blk >> 6;
    int t0 = (blk & 63) << 6;
    for (int idx = threadIdx.x; idx < 64 * DIM; idx += 256) {
        int d = idx >> 6, i = idx & 63;
        tile[i][d] = in[((size_t)d * NB + b) * NTOK + t0 + i];
    }
    __syncthreads();
    float* op = out + ((size_t)b * NTOK + t0) * DIM;
    for (int idx = threadIdx.x; idx < 64 * DIM; idx += 256) {
        int i = idx / DIM, d = idx - i * DIM;
        op[idx] = tile[i][d];
    }
}

// ---------------- unembed: (31,4096,60) -> (60,31,4096) ----------------
__global__ __launch_bounds__(256) void unembed_t(const float* __restrict__ in,
                                                 float* __restrict__ out)
{
    __shared__ float tile[64][61];
    int blk = blockIdx.x;
    int b  = blk >> 6;
    int t0 = (blk & 63) << 6;
    const float* ip = in + ((size_t)b * NTOK + t0) * DIM;
    for (int idx = threadIdx.x; idx < 64 * DIM; idx += 256) {
        int i = idx / DIM, d = idx - i * DIM;
        tile[i][d] = ip[idx];
    }
    __syncthreads();
    for (int idx = threadIdx.x; idx < 64 * DIM; idx += 256) {
        int d = idx >> 6, i = idx & 63;
        out[((size_t)d * NB + b) * NTOK + t0 + i] = tile[i][d];
    }
}

// ---------------- fused window attention (MFMA) ----------------
// One block per window. 256 threads = 4 waves; wave w owns query rows 16w..16w+15.
__global__ __launch_bounds__(256) void swin_attn(
    const float* __restrict__ xin, float* __restrict__ xout,
    const float* __restrict__ g1, const float* __restrict__ b1,
    const float* __restrict__ qkv_w,   // (180,60)
    const float* __restrict__ qkv_b,   // (180)
    const float* __restrict__ rpb,     // (225,6)
    const float* __restrict__ proj_w,  // (60,60)
    const float* __restrict__ proj_b,  // (60)
    int shift)
{
    // bf16 LDS, strides multiple of 8 shorts (16B) and non-pow2 bank step
    __shared__ __attribute__((aligned(16))) short xn[64][72];      //  9216 B (k pad 60..71 = 0)
    __shared__ __attribute__((aligned(16))) short wqkv[192][72];   // 27648 B
    __shared__ __attribute__((aligned(16))) short Qs[6][64][40];   // 30720 B (k 10..31 = 0)
    __shared__ __attribute__((aligned(16))) short Ks[6][64][40];   // 30720 B
    __shared__ __attribute__((aligned(16))) short vT[6][16][72];   // 13824 B (e rows 10..15 = 0)
    __shared__ __attribute__((aligned(16))) short sc[64][72];      //  9216 B
    __shared__ __attribute__((aligned(16))) short oac[64][72];     //  9216 B
    __shared__ __attribute__((aligned(16))) short wproj[64][72];   //  9216 B
    __shared__ float rpl[225 * 6];                                 //  5400 B   total ~145 KB

    const int tid = threadIdx.x;
    const int blk = blockIdx.x;
    const int b  = blk >> 6;
    const int w  = blk & 63;
    const int wy = w >> 3, wx = w & 7;

    // ---- phase A: zero pads + stage weights + LN -> xn ----
    {
        int* z = (int*)Qs;   // Qs,Ks contiguous? not guaranteed -> zero each separately
        for (int i = tid; i < 6 * 64 * 40 / 2; i += 256) ((int*)Qs)[i] = 0;
        for (int i = tid; i < 6 * 64 * 40 / 2; i += 256) ((int*)Ks)[i] = 0;
        for (int i = tid; i < 6 * 16 * 72 / 2; i += 256) ((int*)vT)[i] = 0;
        for (int i = tid; i < 64 * 72 / 2;     i += 256) ((int*)oac)[i] = 0;
        (void)z;
    }
    for (int i = tid; i < 192 * 72; i += 256) {
        int n = i / 72, k = i - n * 72;
        wqkv[n][k] = (n < 180 && k < 60) ? f2b(qkv_w[n * 60 + k]) : (short)0;
    }
    for (int i = tid; i < 64 * 72; i += 256) {
        int n = i / 72, k = i - n * 72;
        wproj[n][k] = (n < 60 && k < 60) ? f2b(proj_w[n * 60 + k]) : (short)0;
    }
    for (int i = tid; i < 225 * 6; i += 256) rpl[i] = rpb[i];

    // LN: 4 threads per token
    {
        const int tk = tid >> 2, l4 = tid & 3;
        const int ty = tk >> 3, tx = tk & 7;
        const int hs = (wy * 8 + ty + shift) & 63;
        const int ws = (wx * 8 + tx + shift) & 63;
        const float* xrow = xin + ((size_t)b * NTOK + hs * 64 + ws) * DIM;
        float xr[15];
        float s = 0.f, s2 = 0.f;
#pragma unroll
        for (int dd = 0; dd < 15; ++dd) {
            float v = xrow[dd * 4 + l4];
            xr[dd] = v; s += v; s2 += v * v;
        }
        s  += __shfl_xor(s, 1);  s  += __shfl_xor(s, 2);
        s2 += __shfl_xor(s2, 1); s2 += __shfl_xor(s2, 2);
        const float mu = s * (1.f / 60.f);
        const float rs = rsqrtf(s2 * (1.f / 60.f) - mu * mu + 1e-5f);
#pragma unroll
        for (int dd = 0; dd < 15; ++dd) {
            int d = dd * 4 + l4;
            xn[tk][d] = f2b((xr[dd] - mu) * rs * g1[d] + b1[d]);
        }
#pragma unroll
        for (int u = 0; u < 3; ++u) xn[tk][60 + l4 * 3 + u] = 0;
    }
    __syncthreads();

    const int wid = tid >> 6, lane = tid & 63;
    const int r16 = lane & 15, g = lane >> 4;
    const int m0 = wid * 16;

    // ---- phase B: qkv GEMM (M=64,N=192,K=64) + scatter to Qs/Ks/vT ----
    {
        bf16x8 a0 = *(const bf16x8*)&xn[m0 + r16][g * 8];
        bf16x8 a1 = *(const bf16x8*)&xn[m0 + r16][32 + g * 8];
#pragma unroll
        for (int nt = 0; nt < 12; ++nt) {
            bf16x8 b0 = *(const bf16x8*)&wqkv[nt * 16 + r16][g * 8];
            bf16x8 b1 = *(const bf16x8*)&wqkv[nt * 16 + r16][32 + g * 8];
            f32x4 acc = {0.f, 0.f, 0.f, 0.f};
            acc = MFMA16(a0, b0, acc);
            acc = MFMA16(a1, b1, acc);
            int c = nt * 16 + r16;
            if (c < 180) {
                float bias = qkv_b[c];
                int which = c / 60;
                int rem = c - which * 60;
                int h = rem / 10, e = rem - h * 10;
#pragma unroll
                for (int r = 0; r < 4; ++r) {
                    int tk = m0 + g * 4 + r;
                    float v = acc[r] + bias;
                    if (which == 0)      Qs[h][tk][e] = f2b(v * QK_SCALE);
                    else if (which == 1) Ks[h][tk][e] = f2b(v);
                    else                 vT[h][e][tk] = f2b(v);
                }
            }
        }
    }
    __syncthreads();

    // ---- phase C: per head: scores -> softmax (in-reg) -> PV ----
    for (int h = 0; h < 6; ++h) {
        bf16x8 qa = *(const bf16x8*)&Qs[h][m0 + r16][g * 8];
        f32x4 s[4];
#pragma unroll
        for (int nt = 0; nt < 4; ++nt) {
            bf16x8 kb = *(const bf16x8*)&Ks[h][nt * 16 + r16][g * 8];
            f32x4 z = {0.f, 0.f, 0.f, 0.f};
            s[nt] = MFMA16(qa, kb, z);
        }
        // bias + mask; value s[nt][r]: row i=m0+g*4+r, col j=nt*16+r16
#pragma unroll
        for (int r = 0; r < 4; ++r) {
            int i = m0 + g * 4 + r;
            int iy = i >> 3, ix = i & 7;
            int him = wy * 8 + iy, wim = wx * 8 + ix;
            int ri = (him < 56 ? 0 : (him < 60 ? 1 : 2)) * 3
                   + (wim < 56 ? 0 : (wim < 60 ? 1 : 2));
#pragma unroll
            for (int nt = 0; nt < 4; ++nt) {
                int j = nt * 16 + r16;
                int jy = j >> 3, jx = j & 7;
                float v = s[nt][r] + rpl[((iy - jy + 7) * 15 + (ix - jx + 7)) * 6 + h];
                if (shift) {
                    int hjm = wy * 8 + jy, wjm = wx * 8 + jx;
                    int rj = (hjm < 56 ? 0 : (hjm < 60 ? 1 : 2)) * 3
                           + (wjm < 56 ? 0 : (wjm < 60 ? 1 : 2));
                    if (ri != rj) v -= 100.f;
                }
                s[nt][r] = v;
            }
        }
        // softmax per row r across 16 lanes x 4 tiles
#pragma unroll
        for (int r = 0; r < 4; ++r) {
            float m = fmaxf(fmaxf(s[0][r], s[1][r]), fmaxf(s[2][r], s[3][r]));
            m = fmaxf(m, __shfl_xor(m, 1));
            m = fmaxf(m, __shfl_xor(m, 2));
            m = fmaxf(m, __shfl_xor(m, 4));
            m = fmaxf(m, __shfl_xor(m, 8));
            float sum = 0.f;
#pragma unroll
            for (int nt = 0; nt < 4; ++nt) {
                float e = __expf(s[nt][r] - m);
                s[nt][r] = e; sum += e;
            }
            sum += __shfl_xor(sum, 1);
            sum += __shfl_xor(sum, 2);
            sum += __shfl_xor(sum, 4);
            sum += __shfl_xor(sum, 8);
            float inv = 1.f / sum;
#pragma unroll
            for (int nt = 0; nt < 4; ++nt)
                sc[m0 + g * 4 + r][nt * 16 + r16] = f2b(s[nt][r] * inv);
        }
        // PV: A = P rows (own wave), B = vT[h] (e x token)
        {
            bf16x8 pa0 = *(const bf16x8*)&sc[m0 + r16][g * 8];
            bf16x8 pa1 = *(const bf16x8*)&sc[m0 + r16][32 + g * 8];
            bf16x8 vb0 = *(const bf16x8*)&vT[h][r16][g * 8];
            bf16x8 vb1 = *(const bf16x8*)&vT[h][r16][32 + g * 8];
            f32x4 o = {0.f, 0.f, 0.f, 0.f};
            o = MFMA16(pa0, vb0, o);
            o = MFMA16(pa1, vb1, o);
            if (r16 < 10) {
#pragma unroll
                for (int r = 0; r < 4; ++r)
                    oac[m0 + g * 4 + r][h * 10 + r16] = f2b(o[r]);
            }
        }
    }
    __syncthreads();

    // ---- phase D: proj GEMM + residual + scatter-store ----
    {
        bf16x8 oa0 = *(const bf16x8*)&oac[m0 + r16][g * 8];
        bf16x8 oa1 = *(const bf16x8*)&oac[m0 + r16][32 + g * 8];
#pragma unroll
        for (int nt = 0; nt < 4; ++nt) {
            bf16x8 pb0 = *(const bf16x8*)&wproj[nt * 16 + r16][g * 8];
            bf16x8 pb1 = *(const bf16x8*)&wproj[nt * 16 + r16][32 + g * 8];
            f32x4 acc = {0.f, 0.f, 0.f, 0.f};
            acc = MFMA16(oa0, pb0, acc);
            acc = MFMA16(oa1, pb1, acc);
            int d = nt * 16 + r16;
            if (d < 60) {
                float bias = proj_b[d];
#pragma unroll
                for (int r = 0; r < 4; ++r) {
                    int t = m0 + g * 4 + r;
                    int ty = t >> 3, tx = t & 7;
                    int hs = (wy * 8 + ty + shift) & 63;
                    int ws = (wx * 8 + tx + shift) & 63;
                    size_t off = ((size_t)b * NTOK + hs * 64 + ws) * DIM + d;
                    xout[off] = xin[off] + acc[r] + bias;
                }
            }
        }
    }
}

// ---------------- fused MLP (MFMA): LN2 + fc1 + GELU + fc2 + residual ----------------
// 64 tokens per block, 256 threads = 4 waves; wave w owns token rows 16w..16w+15.
__global__ __launch_bounds__(256) void swin_mlp(
    const float* __restrict__ xin, float* __restrict__ xout,
    const float* __restrict__ g2, const float* __restrict__ b2,
    const float* __restrict__ fc1_w,   // (240,60)
    const float* __restrict__ fc1_b,   // (240)
    const float* __restrict__ fc2_w,   // (60,240)
    const float* __restrict__ fc2_b)   // (60)
{
    __shared__ __attribute__((aligned(16))) short xn[64][72];     //  9216 B
    __shared__ __attribute__((aligned(16))) short w1[240][72];    // 34560 B
    __shared__ __attribute__((aligned(16))) short hb[64][264];    // 33792 B (k pad 240..263 = 0)
    __shared__ __attribute__((aligned(16))) short w2[64][264];    // 33792 B  total ~109 KB

    const int tid = threadIdx.x;

    for (int i = tid; i < 240 * 72; i += 256) {
        int n = i / 72, k = i - n * 72;
        w1[n][k] = (k < 60) ? f2b(fc1_w[n * 60 + k]) : (short)0;
    }
    for (int i = tid; i < 64 * 264; i += 256) {
        int n = i / 264, k = i - n * 264;
        w2[n][k] = (n < 60 && k < 240) ? f2b(fc2_w[n * 240 + k]) : (short)0;
    }
    for (int i = tid; i < 64 * 24; i += 256) {
        int r = i / 24, k = 240 + (i - (i / 24) * 24);
        hb[r][k] = 0;
    }
    // LN
    {
        const int tk = tid >> 2, l4 = tid & 3;
        const size_t t = (size_t)blockIdx.x * 64 + tk;
        const float* xrow = xin + t * DIM;
        float xr[15];
        float s = 0.f, s2 = 0.f;
#pragma unroll
        for (int dd = 0; dd < 15; ++dd) {
            float v = xrow[dd * 4 + l4];
            xr[dd] = v; s += v; s2 += v * v;
        }
        s  += __shfl_xor(s, 1);  s  += __shfl_xor(s, 2);
        s2 += __shfl_xor(s2, 1); s2 += __shfl_xor(s2, 2);
        const float mu = s * (1.f / 60.f);
        const float rs = rsqrtf(s2 * (1.f / 60.f) - mu * mu + 1e-5f);
#pragma unroll
        for (int dd = 0; dd < 15; ++dd) {
            int d = dd * 4 + l4;
            xn[tk][d] = f2b((xr[dd] - mu) * rs * g2[d] + b2[d]);
        }
#pragma unroll
        for (int u = 0; u < 3; ++u) xn[tk][60 + l4 * 3 + u] = 0;
    }
    __syncthreads();

    const int wid = tid >> 6, lane = tid & 63;
    const int r16 = lane & 15, g = lane >> 4;
    const int m0 = wid * 16;

    // ---- GEMM1: h = GELU(xn @ w1^T + b1)  (M=64,N=240,K=64) ----
    {
        bf16x8 a0 = *(const bf16x8*)&xn[m0 + r16][g * 8];
        bf16x8 a1 = *(const bf16x8*)&xn[m0 + r16][32 + g * 8];
#pragma unroll
        for (int nt = 0; nt < 15; ++nt) {
            bf16x8 b0 = *(const bf16x8*)&w1[nt * 16 + r16][g * 8];
            bf16x8 b1f = *(const bf16x8*)&w1[nt * 16 + r16][32 + g * 8];
            f32x4 acc = {0.f, 0.f, 0.f, 0.f};
            acc = MFMA16(a0, b0, acc);
            acc = MFMA16(a1, b1f, acc);
            int c = nt * 16 + r16;
            float bias = fc1_b[c];
#pragma unroll
            for (int r = 0; r < 4; ++r) {
                float u = acc[r] + bias;
                float ge = 0.5f * u * (1.f + erff(u * 0.70710678118654752f));
                hb[m0 + g * 4 + r][c] = f2b(ge);
            }
        }
    }
    __syncthreads();

    // ---- GEMM2: out = h @ w2^T + b2 + x  (M=64,N=64,K=256) ----
    {
        bf16x8 ha[8];
#pragma unroll
        for (int kk = 0; kk < 8; ++kk)
            ha[kk] = *(const bf16x8*)&hb[m0 + r16][kk * 32 + g * 8];
#pragma unroll
        for (int nt = 0; nt < 4; ++nt) {
            f32x4 acc = {0.f, 0.f, 0.f, 0.f};
#pragma unroll
            for (int kk = 0; kk < 8; ++kk) {
                bf16x8 wb = *(const bf16x8*)&w2[nt * 16 + r16][kk * 32 + g * 8];
                acc = MFMA16(ha[kk], wb, acc);
            }
            int d = nt * 16 + r16;
            if (d < 60) {
                float bias = fc2_b[d];
#pragma unroll
                for (int r = 0; r < 4; ++r) {
                    size_t t = (size_t)blockIdx.x * 64 + m0 + g * 4 + r;
                    size_t off = t * DIM + d;
                    xout[off] = xin[off] + acc[r] + bias;
                }
            }
        }
    }
}

extern "C" void kernel_launch(void* const* d_in, const int* in_sizes, int n_in,
                              void* d_out, int out_size, void* d_ws, size_t ws_size,
                              hipStream_t stream)
{
    const float* x       = (const float*)d_in[0];
    const float* norm1_g = (const float*)d_in[1];
    const float* norm1_b = (const float*)d_in[2];
    const float* qkv_w   = (const float*)d_in[3];
    const float* qkv_b   = (const float*)d_in[4];
    const float* rpb     = (const float*)d_in[5];
    const float* proj_w  = (const float*)d_in[6];
    const float* proj_b  = (const float*)d_in[7];
    const float* norm2_g = (const float*)d_in[8];
    const float* norm2_b = (const float*)d_in[9];
    const float* fc1_w   = (const float*)d_in[10];
    const float* fc1_b   = (const float*)d_in[11];
    const float* fc2_w   = (const float*)d_in[12];
    const float* fc2_b   = (const float*)d_in[13];

    float* ws  = (float*)d_ws;
    float* out = (float*)d_out;

    const int NWG = NB * 64;  // 1984
    dim3 grid(NWG), block(256);

    embed_t<<<grid, block, 0, stream>>>(x, ws);

    for (int i = 0; i < 2; ++i) {
        int shift = (i == 0) ? 0 : 4;
        swin_attn<<<grid, block, 0, stream>>>(
            ws, out,
            norm1_g + i * 60, norm1_b + i * 60,
            qkv_w + i * 180 * 60, qkv_b + i * 180,
            rpb + i * 225 * 6,
            proj_w + i * 60 * 60, proj_b + i * 60,
            shift);
        swin_mlp<<<grid, block, 0, stream>>>(
            out, ws,
            norm2_g + i * 60, norm2_b + i * 60,
            fc1_w + i * 240 * 60, fc1_b + i * 240,
            fc2_w + i * 60 * 240, fc2_b + i * 60);
    }

    unembed_t<<<grid, block, 0, stream>>>(ws, out);
}

// Round 3
// 310.982 us; speedup vs baseline: 12.8718x; 3.3607x over previous
//
#include <hip/hip_runtime.h>
#include <math.h>

// Swin stage: B=31 images, H=W=64 (4096 tokens/img), DIM=60, NH=6, HD=10, WS=8.
// Round 3: pre-packed bf16 weights in ws, bf16 activation ping-pong,
// 2 blocks/CU (LDS <= 80KB), fused embed (attn0) / unembed (mlp1).

#define NB   31
#define NTOK 4096
#define DIM  60
#define NTOT (NB * NTOK)            // 126976 tokens
#define QK_SCALE 0.31622776601683794f

typedef __attribute__((ext_vector_type(8))) short bf16x8;
typedef __attribute__((ext_vector_type(4))) float f32x4;

__device__ __forceinline__ short f2b(float f) {
    union { float f; unsigned u; } v; v.f = f;
    unsigned r = (v.u + 0x7FFFu + ((v.u >> 16) & 1u)) >> 16;  // RNE
    return (short)r;
}
__device__ __forceinline__ float b2f(unsigned short u) {
    union { unsigned u; float f; } v; v.u = ((unsigned)u) << 16;
    return v.f;
}

#define MFMA16(a, b, c) __builtin_amdgcn_mfma_f32_16x16x32_bf16(a, b, c, 0, 0, 0)

// packed-weight layout (shorts, per layer)
#define PK_QKV   0        // [192][72]  head-grouped qkv rows
#define PK_PROJ  13824    // [64][72]
#define PK_W1    18432    // [240][72]
#define PK_W2    35712    // [64][264]
#define PK_RPL   52608    // [1352] bf16
#define PK_STRIDE 54016   // per-layer stride (16B aligned)

// ---------------- pack weights to bf16 (one block per layer) ----------------
__global__ __launch_bounds__(256) void pack_w(
    const float* __restrict__ qkv_w, const float* __restrict__ proj_w,
    const float* __restrict__ fc1_w, const float* __restrict__ fc2_w,
    const float* __restrict__ rpb, short* __restrict__ pk)
{
    const int L = blockIdx.x;
    short* o = pk + (size_t)L * PK_STRIDE;
    const float* qw = qkv_w + L * 10800;
    const float* pw = proj_w + L * 3600;
    const float* w1 = fc1_w + L * 14400;
    const float* w2 = fc2_w + L * 14400;
    const float* rp = rpb + L * 1350;

    // qkv rows regrouped: group p (head triple): [q h(3p..3p+2) 30][k 30][v 30][zero 6]
    for (int i = threadIdx.x; i < 192 * 72; i += 256) {
        int row = i / 72, k = i - row * 72;
        int p = row / 96, rg = row - p * 96;
        short v = 0;
        if (rg < 90 && k < 60) {
            int which = rg / 30, idx = rg - which * 30;
            int h = p * 3 + idx / 10, e = idx - (idx / 10) * 10;
            v = f2b(qw[(which * 60 + h * 10 + e) * 60 + k]);
        }
        o[PK_QKV + i] = v;
    }
    for (int i = threadIdx.x; i < 64 * 72; i += 256) {
        int n = i / 72, k = i - n * 72;
        o[PK_PROJ + i] = (n < 60 && k < 60) ? f2b(pw[n * 60 + k]) : (short)0;
    }
    for (int i = threadIdx.x; i < 240 * 72; i += 256) {
        int n = i / 72, k = i - n * 72;
        o[PK_W1 + i] = (k < 60) ? f2b(w1[n * 60 + k]) : (short)0;
    }
    for (int i = threadIdx.x; i < 64 * 264; i += 256) {
        int n = i / 264, k = i - n * 264;
        o[PK_W2 + i] = (n < 60 && k < 240) ? f2b(w2[n * 240 + k]) : (short)0;
    }
    for (int i = threadIdx.x; i < 1352; i += 256)
        o[PK_RPL + i] = (i < 1350) ? f2b(rp[i]) : (short)0;
}

// ---------------- fused window attention ----------------
// IN_EMBED=1: input is original fp32 (60,31,4096) d-major; else bf16 (31,4096,60).
// Output always bf16 (31,4096,60).
template<int IN_EMBED>
__global__ __launch_bounds__(256) void swin_attn(
    const void* __restrict__ xin_v, unsigned short* __restrict__ xout,
    const float* __restrict__ g1, const float* __restrict__ b1,
    const short* __restrict__ pk,
    const float* __restrict__ qkv_b, const float* __restrict__ proj_b,
    int shift)
{
    __shared__ __attribute__((aligned(16))) short wall[192][72];  // 27648 B
    __shared__ __attribute__((aligned(16))) short xn[64][72];     //  9216 B
    __shared__ __attribute__((aligned(16))) short qk[2][3][64][16]; // 12288 B (later: proj)
    __shared__ __attribute__((aligned(16))) short vT[3][16][72];  //  6912 B
    __shared__ __attribute__((aligned(16))) short sc[64][72];     //  9216 B
    __shared__ __attribute__((aligned(16))) short oac[64][72];    //  9216 B
    __shared__ __attribute__((aligned(16))) short rplb[1352];     //  2704 B  total ~77.2 KB

    const int tid = threadIdx.x, blk = blockIdx.x;
    const int b = blk >> 6, w = blk & 63;
    const int wy = w >> 3, wx = w & 7;

    // ---- phase A: stage packed weights, zero pads, LN -> xn ----
    {
        int4* d = (int4*)&wall[0][0];
        const int4* s = (const int4*)(pk + PK_QKV);
        for (int i = tid; i < 1728; i += 256) d[i] = s[i];
        int4* d2 = (int4*)rplb;
        const int4* s2 = (const int4*)(pk + PK_RPL);
        for (int i = tid; i < 169; i += 256) d2[i] = s2[i];
    }
    // zero pads: qk cols 10..15 (ints 5,6,7 of each 8-int row)
    for (int i = tid; i < 384 * 3; i += 256) {
        int row = i / 3, c = i - row * 3;
        ((int*)qk)[row * 8 + 5 + c] = 0;
    }
    // vT rows 10..15 per head (contiguous 216 ints)
    for (int i = tid; i < 3 * 216; i += 256) {
        int h = i / 216, j = i - h * 216;
        ((int*)&vT[h][10][0])[j] = 0;
    }
    // oac cols 60..63 (ints 30,31 of each 36-int row)
    for (int i = tid; i < 128; i += 256) {
        int r = i >> 1;
        ((int*)oac)[r * 36 + 30 + (i & 1)] = 0;
    }
    // LN: 4 threads per token
    {
        const int tk = tid >> 2, l4 = tid & 3;
        const int ty = tk >> 3, tx = tk & 7;
        const int hs = (wy * 8 + ty + shift) & 63;
        const int wsc = (wx * 8 + tx + shift) & 63;
        const int tok = hs * 64 + wsc;
        float xr[15];
        float s = 0.f, s2 = 0.f;
#pragma unroll
        for (int dd = 0; dd < 15; ++dd) {
            float v;
            if (IN_EMBED) {
                const float* xf = (const float*)xin_v;
                v = xf[(size_t)(dd * 4 + l4) * NTOT + b * NTOK + tok];
            } else {
                const unsigned short* xb = (const unsigned short*)xin_v;
                v = b2f(xb[((size_t)b * NTOK + tok) * DIM + dd * 4 + l4]);
            }
            xr[dd] = v; s += v; s2 += v * v;
        }
        s  += __shfl_xor(s, 1);  s  += __shfl_xor(s, 2);
        s2 += __shfl_xor(s2, 1); s2 += __shfl_xor(s2, 2);
        const float mu = s * (1.f / 60.f);
        const float rs = rsqrtf(s2 * (1.f / 60.f) - mu * mu + 1e-5f);
#pragma unroll
        for (int dd = 0; dd < 15; ++dd) {
            int d = dd * 4 + l4;
            xn[tk][d] = f2b((xr[dd] - mu) * rs * g1[d] + b1[d]);
        }
#pragma unroll
        for (int u = 0; u < 3; ++u) xn[tk][60 + l4 * 3 + u] = 0;
    }
    __syncthreads();

    const int wid = tid >> 6, lane = tid & 63;
    const int r16 = lane & 15, g = lane >> 4;
    const int m0 = wid * 16;

    // precompute rel-pos indices & mask per (r, nt)
    int   relx[4][4];
    float msk[4][4];
#pragma unroll
    for (int r = 0; r < 4; ++r) {
        int i = m0 + g * 4 + r;
        int iy = i >> 3, ix = i & 7;
        int him = wy * 8 + iy, wim = wx * 8 + ix;
        int ri = (him < 56 ? 0 : (him < 60 ? 1 : 2)) * 3
               + (wim < 56 ? 0 : (wim < 60 ? 1 : 2));
#pragma unroll
        for (int nt = 0; nt < 4; ++nt) {
            int j = nt * 16 + r16;
            int jy = j >> 3, jx = j & 7;
            relx[r][nt] = ((iy - jy + 7) * 15 + (ix - jx + 7)) * 6;
            int hjm = wy * 8 + jy, wjm = wx * 8 + jx;
            int rj = (hjm < 56 ? 0 : (hjm < 60 ? 1 : 2)) * 3
                   + (wjm < 56 ? 0 : (wjm < 60 ? 1 : 2));
            msk[r][nt] = (shift && ri != rj) ? -100.f : 0.f;
        }
    }

    bf16x8 a0 = *(const bf16x8*)&xn[m0 + r16][g * 8];
    bf16x8 a1 = *(const bf16x8*)&xn[m0 + r16][32 + g * 8];

    // ---- two passes over head triples ----
    for (int p = 0; p < 2; ++p) {
        // phase B_p: qkv GEMM for this head group (N=96)
#pragma unroll
        for (int nt = 0; nt < 6; ++nt) {
            const short* wr = &wall[p * 96 + nt * 16 + r16][0];
            bf16x8 b0 = *(const bf16x8*)(wr + g * 8);
            bf16x8 b1f = *(const bf16x8*)(wr + 32 + g * 8);
            f32x4 acc = {0.f, 0.f, 0.f, 0.f};
            acc = MFMA16(a0, b0, acc);
            acc = MFMA16(a1, b1f, acc);
            int c = nt * 16 + r16;
            if (c < 90) {
                int which = c / 30;
                int idx = c - which * 30;
                int hl = idx / 10, e = idx - hl * 10;
                float bias = qkv_b[which * 60 + (p * 3 + hl) * 10 + e];
#pragma unroll
                for (int r = 0; r < 4; ++r) {
                    int tk2 = m0 + g * 4 + r;
                    float v = acc[r] + bias;
                    if (which == 0)      qk[0][hl][tk2][e] = f2b(v * QK_SCALE);
                    else if (which == 1) qk[1][hl][tk2][e] = f2b(v);
                    else                 vT[hl][e][tk2] = f2b(v);
                }
            }
        }
        __syncthreads();

        // phase C_p: per head (wave-local; no barriers inside)
#pragma unroll
        for (int hl = 0; hl < 3; ++hl) {
            const int h = p * 3 + hl;
            bf16x8 qa = {0, 0, 0, 0, 0, 0, 0, 0};
            if (g < 2) qa = *(const bf16x8*)&qk[0][hl][m0 + r16][g * 8];
            f32x4 s[4];
#pragma unroll
            for (int nt = 0; nt < 4; ++nt) {
                bf16x8 kb = {0, 0, 0, 0, 0, 0, 0, 0};
                if (g < 2) kb = *(const bf16x8*)&qk[1][hl][nt * 16 + r16][g * 8];
                f32x4 z = {0.f, 0.f, 0.f, 0.f};
                s[nt] = MFMA16(qa, kb, z);
            }
            // bias + mask
#pragma unroll
            for (int r = 0; r < 4; ++r)
#pragma unroll
                for (int nt = 0; nt < 4; ++nt)
                    s[nt][r] += b2f((unsigned short)rplb[relx[r][nt] + h]) + msk[r][nt];
            // softmax (unnormalized exp to sc; keep 1/sum per row)
            float inv[4];
#pragma unroll
            for (int r = 0; r < 4; ++r) {
                float m = fmaxf(fmaxf(s[0][r], s[1][r]), fmaxf(s[2][r], s[3][r]));
                m = fmaxf(m, __shfl_xor(m, 1));
                m = fmaxf(m, __shfl_xor(m, 2));
                m = fmaxf(m, __shfl_xor(m, 4));
                m = fmaxf(m, __shfl_xor(m, 8));
                float sum = 0.f;
#pragma unroll
                for (int nt = 0; nt < 4; ++nt) {
                    float e = __expf(s[nt][r] - m);
                    s[nt][r] = e; sum += e;
                }
                sum += __shfl_xor(sum, 1);
                sum += __shfl_xor(sum, 2);
                sum += __shfl_xor(sum, 4);
                sum += __shfl_xor(sum, 8);
                inv[r] = 1.f / sum;
#pragma unroll
                for (int nt = 0; nt < 4; ++nt)
                    sc[m0 + g * 4 + r][nt * 16 + r16] = f2b(s[nt][r]);
            }
            // PV
            {
                bf16x8 pa0 = *(const bf16x8*)&sc[m0 + r16][g * 8];
                bf16x8 pa1 = *(const bf16x8*)&sc[m0 + r16][32 + g * 8];
                bf16x8 vb0 = *(const bf16x8*)&vT[hl][r16][g * 8];
                bf16x8 vb1 = *(const bf16x8*)&vT[hl][r16][32 + g * 8];
                f32x4 o = {0.f, 0.f, 0.f, 0.f};
                o = MFMA16(pa0, vb0, o);
                o = MFMA16(pa1, vb1, o);
                if (r16 < 10) {
#pragma unroll
                    for (int r = 0; r < 4; ++r)
                        oac[m0 + g * 4 + r][h * 10 + r16] = f2b(o[r] * inv[r]);
                }
            }
        }
        __syncthreads();
    }

    // stage proj weights into dead qk buffer
    {
        int4* d = (int4*)&qk[0][0][0][0];
        const int4* s = (const int4*)(pk + PK_PROJ);
        for (int i = tid; i < 576; i += 256) d[i] = s[i];
    }
    __syncthreads();
    short (*wproj)[72] = (short (*)[72])&qk[0][0][0][0];

    // ---- phase D: proj + residual + store ----
    {
        bf16x8 oa0 = *(const bf16x8*)&oac[m0 + r16][g * 8];
        bf16x8 oa1 = *(const bf16x8*)&oac[m0 + r16][32 + g * 8];
#pragma unroll
        for (int nt = 0; nt < 4; ++nt) {
            bf16x8 pb0 = *(const bf16x8*)&wproj[nt * 16 + r16][g * 8];
            bf16x8 pb1 = *(const bf16x8*)&wproj[nt * 16 + r16][32 + g * 8];
            f32x4 acc = {0.f, 0.f, 0.f, 0.f};
            acc = MFMA16(oa0, pb0, acc);
            acc = MFMA16(oa1, pb1, acc);
            int d = nt * 16 + r16;
            if (d < 60) {
                float bias = proj_b[d];
#pragma unroll
                for (int r = 0; r < 4; ++r) {
                    int t = m0 + g * 4 + r;
                    int ty = t >> 3, tx = t & 7;
                    int hs = (wy * 8 + ty + shift) & 63;
                    int wsc = (wx * 8 + tx + shift) & 63;
                    int tok = hs * 64 + wsc;
                    float res;
                    if (IN_EMBED) {
                        const float* xf = (const float*)xin_v;
                        res = xf[(size_t)d * NTOT + b * NTOK + tok];
                    } else {
                        const unsigned short* xb = (const unsigned short*)xin_v;
                        res = b2f(xb[((size_t)b * NTOK + tok) * DIM + d]);
                    }
                    xout[((size_t)b * NTOK + tok) * DIM + d] =
                        (unsigned short)f2b(res + acc[r] + bias);
                }
            }
        }
    }
}

// ---------------- fused MLP ----------------
// OUT_UNEMBED=1: write fp32 (60,31,4096) d-major; else bf16 (31,4096,60).
template<int OUT_UNEMBED>
__global__ __launch_bounds__(256) void swin_mlp(
    const unsigned short* __restrict__ xin, void* __restrict__ xout_v,
    const float* __restrict__ g2, const float* __restrict__ b2,
    const short* __restrict__ pk,
    const float* __restrict__ fc1_b, const float* __restrict__ fc2_b)
{
    __shared__ __attribute__((aligned(16))) short xn[64][72];    //  9216 B
    __shared__ __attribute__((aligned(16))) short hb[64][264];   // 33792 B
    __shared__ __attribute__((aligned(16))) short wu[17280];     // 34560 B (w1 then w2)
    // total ~77.6 KB -> 2 blocks/CU

    const int tid = threadIdx.x, blk = blockIdx.x;

    // stage w1
    {
        int4* d = (int4*)wu;
        const int4* s = (const int4*)(pk + PK_W1);
        for (int i = tid; i < 2160; i += 256) d[i] = s[i];
    }
    // zero hb cols 240..263 (ints 120..131 of each 132-int row)
    for (int i = tid; i < 64 * 12; i += 256) {
        int r = i / 12, c = i - r * 12;
        ((int*)hb)[r * 132 + 120 + c] = 0;
    }
    // LN
    {
        const int tk = tid >> 2, l4 = tid & 3;
        const size_t t = (size_t)blk * 64 + tk;
        const unsigned short* xrow = xin + t * DIM;
        float xr[15];
        float s = 0.f, s2 = 0.f;
#pragma unroll
        for (int dd = 0; dd < 15; ++dd) {
            float v = b2f(xrow[dd * 4 + l4]);
            xr[dd] = v; s += v; s2 += v * v;
        }
        s  += __shfl_xor(s, 1);  s  += __shfl_xor(s, 2);
        s2 += __shfl_xor(s2, 1); s2 += __shfl_xor(s2, 2);
        const float mu = s * (1.f / 60.f);
        const float rs = rsqrtf(s2 * (1.f / 60.f) - mu * mu + 1e-5f);
#pragma unroll
        for (int dd = 0; dd < 15; ++dd) {
            int d = dd * 4 + l4;
            xn[tk][d] = f2b((xr[dd] - mu) * rs * g2[d] + b2[d]);
        }
#pragma unroll
        for (int u = 0; u < 3; ++u) xn[tk][60 + l4 * 3 + u] = 0;
    }
    __syncthreads();

    const int wid = tid >> 6, lane = tid & 63;
    const int r16 = lane & 15, g = lane >> 4;
    const int m0 = wid * 16;

    // ---- GEMM1: h = GELU(xn @ w1^T + b1)  (M=64, N=240, K=64) ----
    {
        short (*w1)[72] = (short (*)[72])wu;
        bf16x8 a0 = *(const bf16x8*)&xn[m0 + r16][g * 8];
        bf16x8 a1 = *(const bf16x8*)&xn[m0 + r16][32 + g * 8];
#pragma unroll
        for (int nt = 0; nt < 15; ++nt) {
            bf16x8 b0 = *(const bf16x8*)&w1[nt * 16 + r16][g * 8];
            bf16x8 b1f = *(const bf16x8*)&w1[nt * 16 + r16][32 + g * 8];
            f32x4 acc = {0.f, 0.f, 0.f, 0.f};
            acc = MFMA16(a0, b0, acc);
            acc = MFMA16(a1, b1f, acc);
            int c = nt * 16 + r16;
            float bias = fc1_b[c];
#pragma unroll
            for (int r = 0; r < 4; ++r) {
                float u = acc[r] + bias;
                // tanh-form GELU via sigmoid: gelu = u * sigmoid(1.595769*u + 0.0713548*u^3)
                float zz = 1.5957691216057308f * u + 0.07135481178528657f * (u * u * u);
                float ge = u * __builtin_amdgcn_rcpf(1.f + __expf(-zz));
                hb[m0 + g * 4 + r][c] = f2b(ge);
            }
        }
    }
    __syncthreads();

    // stage w2 over w1
    {
        int4* d = (int4*)wu;
        const int4* s = (const int4*)(pk + PK_W2);
        for (int i = tid; i < 2112; i += 256) d[i] = s[i];
    }
    __syncthreads();

    // ---- GEMM2: out = h @ w2^T + b2 + x  (M=64, N=64, K=256) ----
    {
        short (*w2)[264] = (short (*)[264])wu;
        bf16x8 ha[8];
#pragma unroll
        for (int kk = 0; kk < 8; ++kk)
            ha[kk] = *(const bf16x8*)&hb[m0 + r16][kk * 32 + g * 8];
#pragma unroll
        for (int nt = 0; nt < 4; ++nt) {
            f32x4 acc = {0.f, 0.f, 0.f, 0.f};
#pragma unroll
            for (int kk = 0; kk < 8; ++kk) {
                bf16x8 wb = *(const bf16x8*)&w2[nt * 16 + r16][kk * 32 + g * 8];
                acc = MFMA16(ha[kk], wb, acc);
            }
            int d = nt * 16 + r16;
            if (d < 60) {
                float bias = fc2_b[d];
#pragma unroll
                for (int r = 0; r < 4; ++r) {
                    size_t tg = (size_t)blk * 64 + m0 + g * 4 + r;
                    float res = b2f(xin[tg * DIM + d]);
                    float v = res + acc[r] + bias;
                    if (OUT_UNEMBED)
                        ((float*)xout_v)[(size_t)d * NTOT + tg] = v;
                    else
                        ((unsigned short*)xout_v)[tg * DIM + d] = (unsigned short)f2b(v);
                }
            }
        }
    }
}

extern "C" void kernel_launch(void* const* d_in, const int* in_sizes, int n_in,
                              void* d_out, int out_size, void* d_ws, size_t ws_size,
                              hipStream_t stream)
{
    const float* x       = (const float*)d_in[0];
    const float* norm1_g = (const float*)d_in[1];
    const float* norm1_b = (const float*)d_in[2];
    const float* qkv_w   = (const float*)d_in[3];
    const float* qkv_b   = (const float*)d_in[4];
    const float* rpb     = (const float*)d_in[5];
    const float* proj_w  = (const float*)d_in[6];
    const float* proj_b  = (const float*)d_in[7];
    const float* norm2_g = (const float*)d_in[8];
    const float* norm2_b = (const float*)d_in[9];
    const float* fc1_w   = (const float*)d_in[10];
    const float* fc1_b   = (const float*)d_in[11];
    const float* fc2_w   = (const float*)d_in[12];
    const float* fc2_b   = (const float*)d_in[13];

    // ws layout: bufA bf16 activations (15,237,120 B) | packed weights (~216 KB)
    unsigned short* bufA = (unsigned short*)d_ws;
    short* pk = (short*)((char*)d_ws + (size_t)NTOT * DIM * 2);
    // bufB: second half of d_out (fp32 buffer) as bf16
    unsigned short* bufB = (unsigned short*)d_out + (size_t)NTOT * DIM;

    dim3 grid(NB * 64), block(256);

    pack_w<<<dim3(2), block, 0, stream>>>(qkv_w, proj_w, fc1_w, fc2_w, rpb, pk);

    // layer 0
    swin_attn<1><<<grid, block, 0, stream>>>(
        (const void*)x, bufA, norm1_g, norm1_b, pk, qkv_b, proj_b, 0);
    swin_mlp<0><<<grid, block, 0, stream>>>(
        bufA, (void*)bufB, norm2_g, norm2_b, pk, fc1_b, fc2_b);
    // layer 1
    swin_attn<0><<<grid, block, 0, stream>>>(
        (const void*)bufB, bufA, norm1_g + 60, norm1_b + 60, pk + PK_STRIDE,
        qkv_b + 180, proj_b + 60, 4);
    swin_mlp<1><<<grid, block, 0, stream>>>(
        bufA, d_out, norm2_g + 60, norm2_b + 60, pk + PK_STRIDE,
        fc1_b + 240, fc2_b + 60);

    (void)ws_size; (void)in_sizes; (void)n_in; (void)out_size;
}

// Round 4
// 201.083 us; speedup vs baseline: 19.9067x; 1.5465x over previous
//
#include <hip/hip_runtime.h>
#include <math.h>

// Swin stage: B=31 images, H=W=64 (4096 tok/img), DIM=60, NH=6, HD=10, WS=8.
// Round 4: one fused kernel per layer (LN1+attn+proj+res+LN2+MLP+res),
// weights read directly from L2 (packed bf16), swapped-QK^T in-register
// softmax (no score LDS buffer), bias+mask precomputed table.
// LDS 38.7KB -> 4 blocks/CU.

#define NB 31
#define NTOK 4096
#define DIM 60
#define NTOT (NB*NTOK)
#define QK_SCALE 0.31622776601683794f

typedef __attribute__((ext_vector_type(8))) short bf16x8;
typedef __attribute__((ext_vector_type(4))) float f32x4;

__device__ __forceinline__ short f2b(float f){
    union{float f;unsigned u;}v; v.f=f;
    unsigned r=(v.u+0x7FFFu+((v.u>>16)&1u))>>16; return (short)r;
}
__device__ __forceinline__ float b2f(unsigned short u){
    union{unsigned u;float f;}v; v.u=((unsigned)u)<<16; return v.f;
}
__device__ __forceinline__ unsigned pk2(float a,float b){
    return (unsigned)(unsigned short)f2b(a) | ((unsigned)(unsigned short)f2b(b)<<16);
}

#define MFMA16(a,b,c) __builtin_amdgcn_mfma_f32_16x16x32_bf16(a,b,c,0,0,0)

// packed-weight layout per layer (shorts)
#define PK_QKV   0        // [192][72] head-grouped (2 triples x [q30|k30|v30|pad6])
#define PK_PROJ  13824    // [64][72]
#define PK_W1    18432    // [240][72]
#define PK_W2    35712    // [64][264]
#define PK_BIAS  52608    // [4][6][64][64] bias+mask, [class][h][j][i]
#define PK_STRIDE 150912

// ---------------- pack weights + bias tables (grid (2, 8)) ----------------
__global__ __launch_bounds__(256) void pack_w(
    const float* __restrict__ qkv_w, const float* __restrict__ proj_w,
    const float* __restrict__ fc1_w, const float* __restrict__ fc2_w,
    const float* __restrict__ rpb, short* __restrict__ pk)
{
    const int L = blockIdx.x;
    short* o = pk + (size_t)L * PK_STRIDE;
    const float* qw = qkv_w + L * 10800;
    const float* pw = proj_w + L * 3600;
    const float* w1 = fc1_w + L * 14400;
    const float* w2 = fc2_w + L * 14400;
    const float* rp = rpb + L * 1350;
    const int t0 = blockIdx.y * 256 + threadIdx.x;
    const int STP = 256 * 8;

    for (int i = t0; i < 192 * 72; i += STP) {
        int row = i / 72, k = i - row * 72;
        int p = row / 96, rg = row - p * 96;
        short v = 0;
        if (rg < 90 && k < 60) {
            int which = rg / 30, idx = rg - which * 30;
            int h = p * 3 + idx / 10, e = idx - (idx / 10) * 10;
            v = f2b(qw[(which * 60 + h * 10 + e) * 60 + k]);
        }
        o[PK_QKV + i] = v;
    }
    for (int i = t0; i < 64 * 72; i += STP) {
        int n = i / 72, k = i - n * 72;
        o[PK_PROJ + i] = (n < 60 && k < 60) ? f2b(pw[n * 60 + k]) : (short)0;
    }
    for (int i = t0; i < 240 * 72; i += STP) {
        int n = i / 72, k = i - n * 72;
        o[PK_W1 + i] = (k < 60) ? f2b(w1[n * 60 + k]) : (short)0;
    }
    for (int i = t0; i < 64 * 264; i += STP) {
        int n = i / 264, k = i - n * 264;
        o[PK_W2 + i] = (n < 60 && k < 240) ? f2b(w2[n * 240 + k]) : (short)0;
    }
    // bias+mask table: [class][h][j][i]
    for (int i = t0; i < 4 * 6 * 4096; i += STP) {
        int c = i >> 14, rem = i & 16383;
        int h = rem >> 12; rem &= 4095;
        int j = rem >> 6, ii = rem & 63;
        int iy = ii >> 3, ix = ii & 7, jy = j >> 3, jx = j & 7;
        float v = rp[((iy - jy + 7) * 15 + (ix - jx + 7)) * 6 + h];
        int wyv = (c & 2) ? 7 : 0, wxv = (c & 1) ? 7 : 0;
        int riy = wyv < 7 ? 0 : (iy < 4 ? 1 : 2);
        int rix = wxv < 7 ? 0 : (ix < 4 ? 1 : 2);
        int rjy = wyv < 7 ? 0 : (jy < 4 ? 1 : 2);
        int rjx = wxv < 7 ? 0 : (jx < 4 ? 1 : 2);
        if (riy * 3 + rix != rjy * 3 + rjx) v -= 100.f;
        o[PK_BIAS + i] = f2b(v);
    }
}

// ---------------- fused layer: LN1+attn+proj+res + LN2+MLP+res ----------------
// L=0: in fp32 (60,NTOT) embed-layout, shift 0, out bf16 (NTOT,60)
// L=1: in bf16 (NTOT,60), shift 4, out fp32 (60,NTOT)
template<int L>
__global__ __launch_bounds__(256, 4) void swin_layer(
    const void* __restrict__ xin_v, void* __restrict__ xout_v,
    const float* __restrict__ g1, const float* __restrict__ b1,
    const float* __restrict__ g2, const float* __restrict__ b2,
    const short* __restrict__ pk,
    const float* __restrict__ qkv_b, const float* __restrict__ proj_b,
    const float* __restrict__ fc1_b, const float* __restrict__ fc2_b)
{
    __shared__ __attribute__((aligned(16))) short S[19328];   // 38656 B
    short (*xnY)[72]  = (short(*)[72]) S;            // xn -> later y
    short (*qk2)[104] = (short(*)[104])(S + 4608);   // [64]: Q h0,h1,h2 @0,16,32; K @48,64,80
    short (*vTf)[72]  = (short(*)[72]) (S + 11264);  // [3*16][72]  v^T per head
    short (*oac)[72]  = (short(*)[72]) (S + 14720);  // attn out -> later ln2
    short (*hb)[136]  = (short(*)[136])(S + 4608);   // MLP hidden (aliases qk2+vTf)
    short (*ln2)[72]  = oac;

    const bf16x8 Z8 = {0,0,0,0,0,0,0,0};
    const f32x4  Z4 = {0.f,0.f,0.f,0.f};

    const int tid = threadIdx.x, blk = blockIdx.x;
    const int b = blk >> 6, w = blk & 63, wy = w >> 3, wx = w & 7;
    const int shift = L ? 4 : 0;
    const int cls = L ? (((wy == 7) ? 2 : 0) + ((wx == 7) ? 1 : 0)) : 0;

    const float* xf = (const float*)xin_v;
    const unsigned short* xb = (const unsigned short*)xin_v;

    // ---- A: zero pads (Q/K e-cols 10..15 per 16-block; oac cols 60..63) ----
    for (int i = tid; i < 64 * 36; i += 256) {
        int row = i / 36, z = i - row * 36;
        int bc = z / 6, rem = z - bc * 6;
        qk2[row][bc * 16 + 10 + rem] = 0;
    }
    for (int i = tid; i < 128; i += 256) {        // 64 rows x 2 ints
        int row = i >> 1;
        *(int*)&oac[row][60 + ((i & 1) << 1)] = 0;
    }
    // ---- LN1 -> xn ----
    {
        const int tk = tid >> 2, l4 = tid & 3;
        const int ty = tk >> 3, tx = tk & 7;
        const int tok = (((wy * 8 + ty + shift) & 63) << 6) + ((wx * 8 + tx + shift) & 63);
        float xr[15]; float s = 0.f, s2 = 0.f;
#pragma unroll
        for (int dd = 0; dd < 15; ++dd) {
            float v;
            if (L == 0) v = xf[(size_t)(dd * 4 + l4) * NTOT + b * NTOK + tok];
            else        v = b2f(xb[((size_t)b * NTOK + tok) * DIM + dd * 4 + l4]);
            xr[dd] = v; s += v; s2 += v * v;
        }
        s  += __shfl_xor(s, 1);  s  += __shfl_xor(s, 2);
        s2 += __shfl_xor(s2, 1); s2 += __shfl_xor(s2, 2);
        const float mu = s * (1.f / 60.f);
        const float rs = rsqrtf(s2 * (1.f / 60.f) - mu * mu + 1e-5f);
#pragma unroll
        for (int dd = 0; dd < 15; ++dd) {
            int d = dd * 4 + l4;
            xnY[tk][d] = f2b((xr[dd] - mu) * rs * g1[d] + b1[d]);
        }
#pragma unroll
        for (int u = 0; u < 3; ++u) xnY[tk][60 + l4 * 3 + u] = 0;
    }

    const int lane = tid & 63;
    const int r16 = lane & 15, g = lane >> 4;
    const int m0 = (tid >> 6) << 4;

    // source-token (after roll) for the 4 output rows this lane owns
    int tok4[4];
#pragma unroll
    for (int r = 0; r < 4; ++r) {
        int row = m0 + g * 4 + r;
        tok4[r] = (((wy * 8 + (row >> 3) + shift) & 63) << 6)
                + ((wx * 8 + (row & 7) + shift) & 63);
    }

    // xn A-fragments (own-wave rows; in-wave LDS ordering makes this safe)
    bf16x8 a0 = *(const bf16x8*)&xnY[m0 + r16][g * 8];
    bf16x8 a1 = *(const bf16x8*)&xnY[m0 + r16][32 + g * 8];

    const unsigned short* bbase =
        (const unsigned short*)(pk + PK_BIAS) + cls * 24576 + (m0 + r16) + g * 256;

    // ---- attention: two head-triples ----
    for (int p = 0; p < 2; ++p) {
        // B: qkv GEMM for this triple (N=96), weights direct from L2
#pragma unroll
        for (int nt = 0; nt < 6; ++nt) {
            const short* wr = pk + PK_QKV + (size_t)(p * 96 + nt * 16 + r16) * 72;
            bf16x8 w0 = *(const bf16x8*)(wr + g * 8);
            bf16x8 w1v = *(const bf16x8*)(wr + 32 + g * 8);
            f32x4 acc = MFMA16(a0, w0, Z4);
            acc = MFMA16(a1, w1v, acc);
            int c = nt * 16 + r16;
            if (c < 90) {
                int which = c / 30, idx = c - which * 30;
                int hl = idx / 10, e = idx - hl * 10;
                float bias = qkv_b[which * 60 + (p * 3 + hl) * 10 + e];
                if (which == 0) {
#pragma unroll
                    for (int r = 0; r < 4; ++r)
                        qk2[m0 + g * 4 + r][hl * 16 + e] = f2b((acc[r] + bias) * QK_SCALE);
                } else if (which == 1) {
#pragma unroll
                    for (int r = 0; r < 4; ++r)
                        qk2[m0 + g * 4 + r][48 + hl * 16 + e] = f2b(acc[r] + bias);
                } else {
#pragma unroll
                    for (int r = 0; r < 2; ++r)
                        *(unsigned*)&vTf[hl * 16 + e][m0 + g * 4 + r * 2] =
                            pk2(acc[r * 2] + bias, acc[r * 2 + 1] + bias);
                }
            }
        }
        __syncthreads();

        // C: per head — swapped QK^T, in-register softmax, in-register P frags, PV
        for (int hl = 0; hl < 3; ++hl) {
            const int h = p * 3 + hl;
            bf16x8 qa = Z8;
            if (g < 2) qa = *(const bf16x8*)&qk2[m0 + r16][hl * 16 + g * 8];
            f32x4 sv[4];
#pragma unroll
            for (int nt = 0; nt < 4; ++nt) {
                bf16x8 kb = Z8;
                if (g < 2) kb = *(const bf16x8*)&qk2[nt * 16 + r16][48 + hl * 16 + g * 8];
                sv[nt] = MFMA16(kb, qa, Z4);   // S^T: j=nt*16+g*4+reg, i=m0+r16
            }
            const unsigned short* bp = bbase + h * 4096;
#pragma unroll
            for (int nt = 0; nt < 4; ++nt)
#pragma unroll
                for (int r = 0; r < 4; ++r)
                    sv[nt][r] += b2f(bp[nt * 1024 + r * 64]);
            // softmax over j (16 per lane + reduce across g-groups)
            float mx = -1e30f;
#pragma unroll
            for (int nt = 0; nt < 4; ++nt)
#pragma unroll
                for (int r = 0; r < 4; ++r) mx = fmaxf(mx, sv[nt][r]);
            mx = fmaxf(mx, __shfl_xor(mx, 16));
            mx = fmaxf(mx, __shfl_xor(mx, 32));
            float sum = 0.f;
#pragma unroll
            for (int nt = 0; nt < 4; ++nt)
#pragma unroll
                for (int r = 0; r < 4; ++r) {
                    float e = __expf(sv[nt][r] - mx);
                    sv[nt][r] = e; sum += e;
                }
            sum += __shfl_xor(sum, 16);
            sum += __shfl_xor(sum, 32);
            const float inv = 1.f / sum;
            // pack P (bf16 pairs) and redistribute to PV B-fragment layout
            unsigned qd00 = pk2(sv[0][0], sv[0][1]), qd01 = pk2(sv[0][2], sv[0][3]);
            unsigned qd10 = pk2(sv[1][0], sv[1][1]), qd11 = pk2(sv[1][2], sv[1][3]);
            unsigned qd20 = pk2(sv[2][0], sv[2][1]), qd21 = pk2(sv[2][2], sv[2][3]);
            unsigned qd30 = pk2(sv[3][0], sv[3][1]), qd31 = pk2(sv[3][2], sv[3][3]);
            const int sA = (r16 + ((g & 1) << 5)) << 2;
            const int sB = sA + 64;
            const bool hi = (g >> 1) & 1;
            union { unsigned u[4]; bf16x8 v; } pb0, pb1;
            {
                unsigned x0 = __builtin_amdgcn_ds_bpermute(sA, (int)qd00);
                unsigned y0 = __builtin_amdgcn_ds_bpermute(sA, (int)qd10);
                pb0.u[0] = hi ? y0 : x0;
                unsigned x1 = __builtin_amdgcn_ds_bpermute(sA, (int)qd01);
                unsigned y1 = __builtin_amdgcn_ds_bpermute(sA, (int)qd11);
                pb0.u[1] = hi ? y1 : x1;
                unsigned x2 = __builtin_amdgcn_ds_bpermute(sB, (int)qd00);
                unsigned y2 = __builtin_amdgcn_ds_bpermute(sB, (int)qd10);
                pb0.u[2] = hi ? y2 : x2;
                unsigned x3 = __builtin_amdgcn_ds_bpermute(sB, (int)qd01);
                unsigned y3 = __builtin_amdgcn_ds_bpermute(sB, (int)qd11);
                pb0.u[3] = hi ? y3 : x3;
                unsigned u0 = __builtin_amdgcn_ds_bpermute(sA, (int)qd20);
                unsigned v0 = __builtin_amdgcn_ds_bpermute(sA, (int)qd30);
                pb1.u[0] = hi ? v0 : u0;
                unsigned u1 = __builtin_amdgcn_ds_bpermute(sA, (int)qd21);
                unsigned v1 = __builtin_amdgcn_ds_bpermute(sA, (int)qd31);
                pb1.u[1] = hi ? v1 : u1;
                unsigned u2 = __builtin_amdgcn_ds_bpermute(sB, (int)qd20);
                unsigned v2 = __builtin_amdgcn_ds_bpermute(sB, (int)qd30);
                pb1.u[2] = hi ? v2 : u2;
                unsigned u3 = __builtin_amdgcn_ds_bpermute(sB, (int)qd21);
                unsigned v3 = __builtin_amdgcn_ds_bpermute(sB, (int)qd31);
                pb1.u[3] = hi ? v3 : u3;
            }
            // PV: O^T[d][i], A = v^T (rows d), B = P^T
            bf16x8 va0 = *(const bf16x8*)&vTf[hl * 16 + r16][g * 8];
            bf16x8 va1 = *(const bf16x8*)&vTf[hl * 16 + r16][32 + g * 8];
            f32x4 o = MFMA16(va0, pb0.v, Z4);
            o = MFMA16(va1, pb1.v, o);
            // store: lane holds d=g*4+reg (valid<10), i=m0+r16
            if (g < 2) {
                *(unsigned*)&oac[m0 + r16][h * 10 + g * 4]     = pk2(o[0] * inv, o[1] * inv);
                *(unsigned*)&oac[m0 + r16][h * 10 + g * 4 + 2] = pk2(o[2] * inv, o[3] * inv);
            } else if (g == 2) {
                *(unsigned*)&oac[m0 + r16][h * 10 + 8] = pk2(o[0] * inv, o[1] * inv);
            }
        }
        __syncthreads();
    }

    // ---- D: proj + residual -> y (LDS, overwrites xn) ----
    {
        bf16x8 oa0 = *(const bf16x8*)&oac[m0 + r16][g * 8];
        bf16x8 oa1 = *(const bf16x8*)&oac[m0 + r16][32 + g * 8];
#pragma unroll
        for (int nt = 0; nt < 4; ++nt) {
            const short* wr = pk + PK_PROJ + (size_t)(nt * 16 + r16) * 72;
            bf16x8 w0 = *(const bf16x8*)(wr + g * 8);
            bf16x8 w1v = *(const bf16x8*)(wr + 32 + g * 8);
            f32x4 acc = MFMA16(oa0, w0, Z4);
            acc = MFMA16(oa1, w1v, acc);
            int d = nt * 16 + r16;
            if (d < 60) {
                float bias = proj_b[d];
#pragma unroll
                for (int r = 0; r < 4; ++r) {
                    float res;
                    if (L == 0) res = xf[(size_t)d * NTOT + b * NTOK + tok4[r]];
                    else        res = b2f(xb[((size_t)b * NTOK + tok4[r]) * DIM + d]);
                    xnY[m0 + g * 4 + r][d] = f2b(res + acc[r] + bias);
                }
            }
        }
    }

    // ---- E: LN2 (y -> ln2, in oac region; all wave-local) ----
    {
        const int tk = tid >> 2, l4 = tid & 3;
        float yr[15]; float s = 0.f, s2 = 0.f;
#pragma unroll
        for (int dd = 0; dd < 15; ++dd) {
            float v = b2f((unsigned short)xnY[tk][dd * 4 + l4]);
            yr[dd] = v; s += v; s2 += v * v;
        }
        s  += __shfl_xor(s, 1);  s  += __shfl_xor(s, 2);
        s2 += __shfl_xor(s2, 1); s2 += __shfl_xor(s2, 2);
        const float mu = s * (1.f / 60.f);
        const float rs = rsqrtf(s2 * (1.f / 60.f) - mu * mu + 1e-5f);
#pragma unroll
        for (int dd = 0; dd < 15; ++dd) {
            int d = dd * 4 + l4;
            ln2[tk][d] = f2b((yr[dd] - mu) * rs * g2[d] + b2[d]);
        }
#pragma unroll
        for (int u = 0; u < 3; ++u) ln2[tk][60 + l4 * 3 + u] = 0;
    }
    __syncthreads();   // protects hb region (qk2/vTf) from late C-readers

    // ---- MLP ----
    bf16x8 la0 = *(const bf16x8*)&ln2[m0 + r16][g * 8];
    bf16x8 la1 = *(const bf16x8*)&ln2[m0 + r16][32 + g * 8];
    f32x4 acc2[4];
#pragma unroll
    for (int nt = 0; nt < 4; ++nt) acc2[nt] = Z4;

    // F: GEMM1 half A (w1 rows 0..127) -> hb cols 0..127
#pragma unroll
    for (int nt = 0; nt < 8; ++nt) {
        const short* wr = pk + PK_W1 + (size_t)(nt * 16 + r16) * 72;
        bf16x8 w0 = *(const bf16x8*)(wr + g * 8);
        bf16x8 w1v = *(const bf16x8*)(wr + 32 + g * 8);
        f32x4 acc = MFMA16(la0, w0, Z4);
        acc = MFMA16(la1, w1v, acc);
        int c = nt * 16 + r16;
        float bias = fc1_b[c];
#pragma unroll
        for (int r = 0; r < 4; ++r) {
            float u = acc[r] + bias;
            float zz = 1.5957691216057308f * u + 0.07135481178528657f * (u * u * u);
            float ge = u * __builtin_amdgcn_rcpf(1.f + __expf(-zz));
            hb[m0 + g * 4 + r][c] = f2b(ge);
        }
    }
    // G: GEMM2 pass 1 (K = 0..127)
#pragma unroll
    for (int kk = 0; kk < 4; ++kk) {
        bf16x8 ha = *(const bf16x8*)&hb[m0 + r16][kk * 32 + g * 8];
#pragma unroll
        for (int nt = 0; nt < 4; ++nt) {
            const short* wr = pk + PK_W2 + (size_t)(nt * 16 + r16) * 264 + kk * 32 + g * 8;
            acc2[nt] = MFMA16(ha, *(const bf16x8*)wr, acc2[nt]);
        }
    }
    // zero hb cols 112..127 (own rows), then half B
    *(int*)&hb[m0 + r16][112 + g * 4]     = 0;
    *(int*)&hb[m0 + r16][112 + g * 4 + 2] = 0;
    // H: GEMM1 half B (w1 rows 128..239) -> hb cols 0..111
#pragma unroll
    for (int nt = 0; nt < 7; ++nt) {
        const short* wr = pk + PK_W1 + (size_t)(128 + nt * 16 + r16) * 72;
        bf16x8 w0 = *(const bf16x8*)(wr + g * 8);
        bf16x8 w1v = *(const bf16x8*)(wr + 32 + g * 8);
        f32x4 acc = MFMA16(la0, w0, Z4);
        acc = MFMA16(la1, w1v, acc);
        int c = nt * 16 + r16;
        float bias = fc1_b[128 + c];
#pragma unroll
        for (int r = 0; r < 4; ++r) {
            float u = acc[r] + bias;
            float zz = 1.5957691216057308f * u + 0.07135481178528657f * (u * u * u);
            float ge = u * __builtin_amdgcn_rcpf(1.f + __expf(-zz));
            hb[m0 + g * 4 + r][c] = f2b(ge);
        }
    }
    // I: GEMM2 pass 2 (K = 128..255; w2 cols 240..263 are zero-padded) + epilogue
#pragma unroll
    for (int kk = 0; kk < 4; ++kk) {
        bf16x8 ha = *(const bf16x8*)&hb[m0 + r16][kk * 32 + g * 8];
#pragma unroll
        for (int nt = 0; nt < 4; ++nt) {
            const short* wr = pk + PK_W2 + (size_t)(nt * 16 + r16) * 264 + 128 + kk * 32 + g * 8;
            acc2[nt] = MFMA16(ha, *(const bf16x8*)wr, acc2[nt]);
        }
    }
#pragma unroll
    for (int nt = 0; nt < 4; ++nt) {
        int d = nt * 16 + r16;
        if (d < 60) {
            float bias = fc2_b[d];
#pragma unroll
            for (int r = 0; r < 4; ++r) {
                float yv = b2f((unsigned short)xnY[m0 + g * 4 + r][d]);
                float v = yv + acc2[nt][r] + bias;
                if (L == 0)
                    ((unsigned short*)xout_v)[((size_t)b * NTOK + tok4[r]) * DIM + d] =
                        (unsigned short)f2b(v);
                else
                    ((float*)xout_v)[(size_t)d * NTOT + b * NTOK + tok4[r]] = v;
            }
        }
    }
}

extern "C" void kernel_launch(void* const* d_in, const int* in_sizes, int n_in,
                              void* d_out, int out_size, void* d_ws, size_t ws_size,
                              hipStream_t stream)
{
    const float* x       = (const float*)d_in[0];
    const float* norm1_g = (const float*)d_in[1];
    const float* norm1_b = (const float*)d_in[2];
    const float* qkv_w   = (const float*)d_in[3];
    const float* qkv_b   = (const float*)d_in[4];
    const float* rpb     = (const float*)d_in[5];
    const float* proj_w  = (const float*)d_in[6];
    const float* proj_b  = (const float*)d_in[7];
    const float* norm2_g = (const float*)d_in[8];
    const float* norm2_b = (const float*)d_in[9];
    const float* fc1_w   = (const float*)d_in[10];
    const float* fc1_b   = (const float*)d_in[11];
    const float* fc2_w   = (const float*)d_in[12];
    const float* fc2_b   = (const float*)d_in[13];

    // ws: bufA bf16 activations (15.24 MB) | packed weights+tables (~0.6 MB)
    unsigned short* bufA = (unsigned short*)d_ws;
    short* pk = (short*)((char*)d_ws + (size_t)NTOT * DIM * 2);

    dim3 block(256);
    pack_w<<<dim3(2, 8), block, 0, stream>>>(qkv_w, proj_w, fc1_w, fc2_w, rpb, pk);

    dim3 grid(NB * 64);
    swin_layer<0><<<grid, block, 0, stream>>>(
        (const void*)x, (void*)bufA,
        norm1_g, norm1_b, norm2_g, norm2_b, pk,
        qkv_b, proj_b, fc1_b, fc2_b);
    swin_layer<1><<<grid, block, 0, stream>>>(
        (const void*)bufA, d_out,
        norm1_g + 60, norm1_b + 60, norm2_g + 60, norm2_b + 60, pk + PK_STRIDE,
        qkv_b + 180, proj_b + 60, fc1_b + 240, fc2_b + 60);

    (void)in_sizes; (void)n_in; (void)out_size; (void)ws_size;
}

// Round 5
// 178.235 us; speedup vs baseline: 22.4584x; 1.1282x over previous
//
#include <hip/hip_runtime.h>
#include <hip/hip_bf16.h>
#include <math.h>

// Swin stage: B=31, H=W=64, DIM=60, NH=6, HD=10, WS=8. Two layers fused
// (one kernel per layer): LN1+attn(+bias/mask C-init)+proj+res+LN2+MLP+res.
// LDS 29.4KB -> 5 blocks/CU. Weights bf16-packed once; bias tables fp32.

#define NB 31
#define NTOK 4096
#define DIM 60
#define NTOT (NB*NTOK)
#define QK_SCALE 0.31622776601683794f

typedef __attribute__((ext_vector_type(8))) short bf16x8;
typedef __attribute__((ext_vector_type(4))) float f32x4;

__device__ __forceinline__ short f2b(float f){
    return __builtin_bit_cast(short, __float2bfloat16(f));
}
__device__ __forceinline__ float b2f(unsigned short u){
    union{unsigned u;float f;}v; v.u=((unsigned)u)<<16; return v.f;
}
__device__ __forceinline__ unsigned pk2(float a,float b){
    return (unsigned)(unsigned short)f2b(a) | ((unsigned)(unsigned short)f2b(b)<<16);
}
#define MFMA16(a,b,c) __builtin_amdgcn_mfma_f32_16x16x32_bf16(a,b,c,0,0,0)

// packed-weight offsets (shorts, per layer)
#define PK_QKV  0        // [192][72] head-grouped, q rows pre-scaled
#define PK_PROJ 13824    // [64][72]
#define PK_W1   18432    // [240][72]
#define PK_W2   35712    // [64][264]
#define PK_STRIDE 52608

// ---------------- pack: weights -> bf16, bias+mask -> fp32 table ----------------
__global__ __launch_bounds__(256) void pack_w(
    const float* __restrict__ qkv_w, const float* __restrict__ proj_w,
    const float* __restrict__ fc1_w, const float* __restrict__ fc2_w,
    const float* __restrict__ rpb, short* __restrict__ pk, float* __restrict__ btab)
{
    const int L = blockIdx.x;
    short* o = pk + (size_t)L * PK_STRIDE;
    const float* qw = qkv_w + L * 10800;
    const float* pw = proj_w + L * 3600;
    const float* w1 = fc1_w + L * 14400;
    const float* w2 = fc2_w + L * 14400;
    const float* rp = rpb + L * 1350;
    const int t0 = blockIdx.y * 256 + threadIdx.x;
    const int STP = 256 * 8;

    for (int i = t0; i < 192 * 72; i += STP) {
        int row = i / 72, k = i - row * 72;
        int p = row / 96, rg = row - p * 96;
        short v = 0;
        if (rg < 90 && k < 60) {
            int which = rg / 30, idx = rg - which * 30;
            int h = p * 3 + idx / 10, e = idx - (idx / 10) * 10;
            float wv = qw[(which * 60 + h * 10 + e) * 60 + k];
            if (which == 0) wv *= QK_SCALE;
            v = f2b(wv);
        }
        o[PK_QKV + i] = v;
    }
    for (int i = t0; i < 64 * 72; i += STP) {
        int n = i / 72, k = i - n * 72;
        o[PK_PROJ + i] = (n < 60 && k < 60) ? f2b(pw[n * 60 + k]) : (short)0;
    }
    for (int i = t0; i < 240 * 72; i += STP) {
        int n = i / 72, k = i - n * 72;
        o[PK_W1 + i] = (k < 60) ? f2b(w1[n * 60 + k]) : (short)0;
    }
    for (int i = t0; i < 64 * 264; i += STP) {
        int n = i / 264, k = i - n * 264;
        o[PK_W2 + i] = (n < 60 && k < 240) ? f2b(w2[n * 240 + k]) : (short)0;
    }
    // fp32 bias+mask table [L][cls][h][i][j]
    float* bo = btab + (size_t)L * 4 * 24576;
    for (int i = t0; i < 4 * 24576; i += STP) {
        int c = i / 24576, rem = i - c * 24576;
        int h = rem >> 12, rem2 = rem & 4095;
        int ii = rem2 >> 6, j = rem2 & 63;
        int iy = ii >> 3, ix = ii & 7, jy = j >> 3, jx = j & 7;
        float v = rp[((iy - jy + 7) * 15 + (ix - jx + 7)) * 6 + h];
        int riy = (c & 2) ? (iy < 4 ? 1 : 2) : 0;
        int rix = (c & 1) ? (ix < 4 ? 1 : 2) : 0;
        int rjy = (c & 2) ? (jy < 4 ? 1 : 2) : 0;
        int rjx = (c & 1) ? (jx < 4 ? 1 : 2) : 0;
        if (riy != rjy || rix != rjx) v -= 100.f;
        bo[i] = v;
    }
}

// ---------------- fused layer ----------------
// L=0: in fp32 (60,NTOT) d-major, shift 0, out bf16 (NTOT,60)
// L=1: in bf16 (NTOT,60), shift 4, out fp32 (60,NTOT)
template<int L>
__global__ __launch_bounds__(256, 5) void swin_layer(
    const void* __restrict__ xin_v, void* __restrict__ xout_v,
    const float* __restrict__ g1, const float* __restrict__ b1,
    const float* __restrict__ g2, const float* __restrict__ b2,
    const short* __restrict__ pk, const float* __restrict__ btab,
    const float* __restrict__ qkv_b, const float* __restrict__ proj_b,
    const float* __restrict__ fc1_b, const float* __restrict__ fc2_b)
{
    // R1: xn -> oac -> y   (stride 72, wave-local rows)
    // R2: qk[64][104]+vT[48][72] -> ln2/hb/sto (stride 136/68f, wave-local rows)
    __shared__ __attribute__((aligned(16))) short R1[64 * 72];    //  9216 B
    __shared__ __attribute__((aligned(16))) short R2[10112];      // 20224 B

    const f32x4 Z4 = {0.f, 0.f, 0.f, 0.f};
    const bf16x8 Z8 = {0, 0, 0, 0, 0, 0, 0, 0};

    const int tid = threadIdx.x, blk = blockIdx.x;
    const int b = blk >> 6, w = blk & 63, wy = w >> 3, wx = w & 7;
    const int shift = L ? 4 : 0;
    const int cls = L ? (((wy == 7) ? 2 : 0) + ((wx == 7) ? 1 : 0)) : 0;

    const float* xf = (const float*)xin_v;
    const unsigned short* xb = (const unsigned short*)xin_v;

    // ---- A: zero Q/K e-pads (cols 10..15 of six 16-blocks) + vT pad rows ----
    for (int i = tid; i < 64 * 18; i += 256) {
        int row = i / 18, t = i - row * 18, bc = t / 3, k = t - bc * 3;
        *(int*)&R2[row * 104 + bc * 16 + 10 + 2 * k] = 0;
    }
    for (int i = tid; i < 3 * 216; i += 256) {
        int hl = i / 216, j = i - hl * 216;
        *(int*)&R2[6656 + (hl * 16 + 10) * 72 + 2 * j] = 0;
    }

    // ---- LN1 -> R1 (wave-local rows) ----
    const int tk = tid >> 2, l4 = tid & 3;
    const int tok = (((wy * 8 + (tk >> 3) + shift) & 63) << 6)
                  + ((wx * 8 + (tk & 7) + shift) & 63);
    if (L == 0) {
        float xr[15]; float s = 0.f, s2 = 0.f;
#pragma unroll
        for (int dd = 0; dd < 15; ++dd) {
            float v = xf[(size_t)(l4 * 15 + dd) * NTOT + b * NTOK + tok];
            xr[dd] = v; s += v; s2 += v * v;
        }
        s  += __shfl_xor(s, 1);  s  += __shfl_xor(s, 2);
        s2 += __shfl_xor(s2, 1); s2 += __shfl_xor(s2, 2);
        const float mu = s * (1.f / 60.f);
        const float rs = rsqrtf(s2 * (1.f / 60.f) - mu * mu + 1e-5f);
#pragma unroll
        for (int dd = 0; dd < 15; ++dd) {
            int d = l4 * 15 + dd;
            R1[tk * 72 + d] = f2b((xr[dd] - mu) * rs * g1[d] + b1[d]);
        }
#pragma unroll
        for (int u = 0; u < 3; ++u) R1[tk * 72 + 60 + l4 * 3 + u] = 0;
    } else {
        float xr[16]; float s = 0.f, s2 = 0.f;
        const int nd = (l4 == 3) ? 6 : 8, c0 = l4 * 16;
        const unsigned* rp_ = (const unsigned*)(xb + ((size_t)b * NTOK + tok) * DIM) + l4 * 8;
#pragma unroll
        for (int j = 0; j < 8; ++j) {
            if (j < nd) {
                unsigned u = rp_[j];
                float v0 = b2f((unsigned short)(u & 0xffff));
                float v1 = b2f((unsigned short)(u >> 16));
                xr[2 * j] = v0; xr[2 * j + 1] = v1;
                s += v0 + v1; s2 += v0 * v0 + v1 * v1;
            }
        }
        s  += __shfl_xor(s, 1);  s  += __shfl_xor(s, 2);
        s2 += __shfl_xor(s2, 1); s2 += __shfl_xor(s2, 2);
        const float mu = s * (1.f / 60.f);
        const float rs = rsqrtf(s2 * (1.f / 60.f) - mu * mu + 1e-5f);
#pragma unroll
        for (int j = 0; j < 8; ++j) {
            if (j < nd) {
                int d = c0 + 2 * j;
                float n0 = (xr[2 * j] - mu) * rs * g1[d] + b1[d];
                float n1 = (xr[2 * j + 1] - mu) * rs * g1[d + 1] + b1[d + 1];
                *(unsigned*)&R1[tk * 72 + d] = pk2(n0, n1);
            }
        }
        if (l4 == 3) {
#pragma unroll
            for (int u = 0; u < 3; ++u) *(unsigned*)&R1[tk * 72 + 60 + 2 * u] = 0;
        }
    }

    const int lane = tid & 63, r16 = lane & 15, g = lane >> 4;
    const int m0 = (tid >> 6) << 4;

    int tok4[4];
#pragma unroll
    for (int r = 0; r < 4; ++r) {
        int row = m0 + g * 4 + r;
        tok4[r] = (((wy * 8 + (row >> 3) + shift) & 63) << 6)
                + ((wx * 8 + (row & 7) + shift) & 63);
    }

    bf16x8 a0 = *(const bf16x8*)&R1[(m0 + r16) * 72 + g * 8];
    bf16x8 a1 = *(const bf16x8*)&R1[(m0 + r16) * 72 + 32 + g * 8];
    const float* btc = btab + (size_t)cls * 24576 + (m0 + r16) * 64;

    // ---- attention: two head-triples ----
    for (int p = 0; p < 2; ++p) {
        // B: qkv GEMM (N=96), bias via C-init splat, scatter q/k/v
#pragma unroll
        for (int nt = 0; nt < 6; ++nt) {
            const short* wr = pk + PK_QKV + (size_t)(p * 96 + nt * 16 + r16) * 72;
            bf16x8 w0 = *(const bf16x8*)(wr + g * 8);
            bf16x8 w1v = *(const bf16x8*)(wr + 32 + g * 8);
            int c = nt * 16 + r16;
            int which = 0, hl = 0, e = 0; float bias = 0.f;
            if (c < 90) {
                which = c / 30; int idx = c - which * 30;
                hl = idx / 10; e = idx - hl * 10;
                bias = qkv_b[which * 60 + (p * 3 + hl) * 10 + e];
                if (which == 0) bias *= QK_SCALE;
            }
            f32x4 acc = {bias, bias, bias, bias};
            acc = MFMA16(a0, w0, acc);
            acc = MFMA16(a1, w1v, acc);
            if (c < 90) {
                if (which == 0) {
#pragma unroll
                    for (int r = 0; r < 4; ++r)
                        R2[(m0 + g * 4 + r) * 104 + hl * 16 + e] = f2b(acc[r]);
                } else if (which == 1) {
#pragma unroll
                    for (int r = 0; r < 4; ++r)
                        R2[(m0 + g * 4 + r) * 104 + 48 + hl * 16 + e] = f2b(acc[r]);
                } else {
#pragma unroll
                    for (int r = 0; r < 2; ++r)
                        *(unsigned*)&R2[6656 + (hl * 16 + e) * 72 + m0 + g * 4 + 2 * r] =
                            pk2(acc[2 * r], acc[2 * r + 1]);
                }
            }
        }
        __syncthreads();

        // C: per head — swapped QK^T with bias C-init, in-reg softmax, PV
        for (int hl = 0; hl < 3; ++hl) {
            const int h = p * 3 + hl;
            bf16x8 qa = Z8;
            if (g < 2) qa = *(const bf16x8*)&R2[(m0 + r16) * 104 + hl * 16 + g * 8];
            const float* bh = btc + h * 4096;
            f32x4 sv[4];
#pragma unroll
            for (int nt = 0; nt < 4; ++nt) {
                bf16x8 kb = Z8;
                if (g < 2) kb = *(const bf16x8*)&R2[(nt * 16 + r16) * 104 + 48 + hl * 16 + g * 8];
                sv[nt] = MFMA16(kb, qa, *(const f32x4*)&bh[nt * 16 + g * 4]);
            }
            float mx = -1e30f;
#pragma unroll
            for (int nt = 0; nt < 4; ++nt)
#pragma unroll
                for (int r = 0; r < 4; ++r) mx = fmaxf(mx, sv[nt][r]);
            mx = fmaxf(mx, __shfl_xor(mx, 16));
            mx = fmaxf(mx, __shfl_xor(mx, 32));
            float sum = 0.f;
#pragma unroll
            for (int nt = 0; nt < 4; ++nt)
#pragma unroll
                for (int r = 0; r < 4; ++r) {
                    float e = __expf(sv[nt][r] - mx);
                    sv[nt][r] = e; sum += e;
                }
            sum += __shfl_xor(sum, 16);
            sum += __shfl_xor(sum, 32);
            const float inv = 1.f / sum;

            unsigned qd00 = pk2(sv[0][0], sv[0][1]), qd01 = pk2(sv[0][2], sv[0][3]);
            unsigned qd10 = pk2(sv[1][0], sv[1][1]), qd11 = pk2(sv[1][2], sv[1][3]);
            unsigned qd20 = pk2(sv[2][0], sv[2][1]), qd21 = pk2(sv[2][2], sv[2][3]);
            unsigned qd30 = pk2(sv[3][0], sv[3][1]), qd31 = pk2(sv[3][2], sv[3][3]);
            const int sA = (r16 + ((g & 1) << 5)) << 2;
            const int sB = sA + 64;
            const bool hi = (g >> 1) & 1;
            union { unsigned u[4]; bf16x8 v; } pb0, pb1;
            {
                unsigned x0 = __builtin_amdgcn_ds_bpermute(sA, (int)qd00);
                unsigned y0 = __builtin_amdgcn_ds_bpermute(sA, (int)qd10);
                pb0.u[0] = hi ? y0 : x0;
                unsigned x1 = __builtin_amdgcn_ds_bpermute(sA, (int)qd01);
                unsigned y1 = __builtin_amdgcn_ds_bpermute(sA, (int)qd11);
                pb0.u[1] = hi ? y1 : x1;
                unsigned x2 = __builtin_amdgcn_ds_bpermute(sB, (int)qd00);
                unsigned y2 = __builtin_amdgcn_ds_bpermute(sB, (int)qd10);
                pb0.u[2] = hi ? y2 : x2;
                unsigned x3 = __builtin_amdgcn_ds_bpermute(sB, (int)qd01);
                unsigned y3 = __builtin_amdgcn_ds_bpermute(sB, (int)qd11);
                pb0.u[3] = hi ? y3 : x3;
                unsigned u0 = __builtin_amdgcn_ds_bpermute(sA, (int)qd20);
                unsigned v0 = __builtin_amdgcn_ds_bpermute(sA, (int)qd30);
                pb1.u[0] = hi ? v0 : u0;
                unsigned u1 = __builtin_amdgcn_ds_bpermute(sA, (int)qd21);
                unsigned v1 = __builtin_amdgcn_ds_bpermute(sA, (int)qd31);
                pb1.u[1] = hi ? v1 : u1;
                unsigned u2 = __builtin_amdgcn_ds_bpermute(sB, (int)qd20);
                unsigned v2 = __builtin_amdgcn_ds_bpermute(sB, (int)qd30);
                pb1.u[2] = hi ? v2 : u2;
                unsigned u3 = __builtin_amdgcn_ds_bpermute(sB, (int)qd21);
                unsigned v3 = __builtin_amdgcn_ds_bpermute(sB, (int)qd31);
                pb1.u[3] = hi ? v3 : u3;
            }
            bf16x8 va0 = *(const bf16x8*)&R2[6656 + (hl * 16 + r16) * 72 + g * 8];
            bf16x8 va1 = *(const bf16x8*)&R2[6656 + (hl * 16 + r16) * 72 + 32 + g * 8];
            f32x4 o = MFMA16(va0, pb0.v, Z4);
            o = MFMA16(va1, pb1.v, o);
            if (g < 2) {
                *(unsigned*)&R1[(m0 + r16) * 72 + h * 10 + g * 4]     = pk2(o[0] * inv, o[1] * inv);
                *(unsigned*)&R1[(m0 + r16) * 72 + h * 10 + g * 4 + 2] = pk2(o[2] * inv, o[3] * inv);
            } else if (g == 2) {
                *(unsigned*)&R1[(m0 + r16) * 72 + h * 10 + 8] = pk2(o[0] * inv, o[1] * inv);
            }
        }
        __syncthreads();
    }

    // ---- D: proj + residual -> y (R1, wave-local overwrite of oac) ----
    {
        bf16x8 oa0 = *(const bf16x8*)&R1[(m0 + r16) * 72 + g * 8];
        bf16x8 oa1 = *(const bf16x8*)&R1[(m0 + r16) * 72 + 32 + g * 8];
#pragma unroll
        for (int nt = 0; nt < 4; ++nt) {
            const short* wr = pk + PK_PROJ + (size_t)(nt * 16 + r16) * 72;
            bf16x8 w0 = *(const bf16x8*)(wr + g * 8);
            bf16x8 w1v = *(const bf16x8*)(wr + 32 + g * 8);
            int d = nt * 16 + r16;
            float pb_ = (d < 60) ? proj_b[d] : 0.f;
            f32x4 acc = {pb_, pb_, pb_, pb_};
            acc = MFMA16(oa0, w0, acc);
            acc = MFMA16(oa1, w1v, acc);
            if (d < 60) {
#pragma unroll
                for (int r = 0; r < 4; ++r) {
                    float res;
                    if (L == 0) res = xf[(size_t)d * NTOT + b * NTOK + tok4[r]];
                    else        res = b2f(xb[((size_t)b * NTOK + tok4[r]) * DIM + d]);
                    R1[(m0 + g * 4 + r) * 72 + d] = f2b(res + acc[r]);
                }
            }
        }
    }

    // ---- E: LN2 (y -> R2 stride-136 rows, wave-local) ----
    {
        float yr[15]; float s = 0.f, s2 = 0.f;
#pragma unroll
        for (int dd = 0; dd < 15; ++dd) {
            float v = b2f((unsigned short)R1[tk * 72 + dd * 4 + l4]);
            yr[dd] = v; s += v; s2 += v * v;
        }
        s  += __shfl_xor(s, 1);  s  += __shfl_xor(s, 2);
        s2 += __shfl_xor(s2, 1); s2 += __shfl_xor(s2, 2);
        const float mu = s * (1.f / 60.f);
        const float rs = rsqrtf(s2 * (1.f / 60.f) - mu * mu + 1e-5f);
#pragma unroll
        for (int dd = 0; dd < 15; ++dd) {
            int d = dd * 4 + l4;
            R2[tk * 136 + d] = f2b((yr[dd] - mu) * rs * g2[d] + b2[d]);
        }
#pragma unroll
        for (int u = 0; u < 3; ++u) R2[tk * 136 + 60 + l4 * 3 + u] = 0;
    }

    bf16x8 la0 = *(const bf16x8*)&R2[(m0 + r16) * 136 + g * 8];
    bf16x8 la1 = *(const bf16x8*)&R2[(m0 + r16) * 136 + 32 + g * 8];

    f32x4 acc2[4];
#pragma unroll
    for (int nt = 0; nt < 4; ++nt) {
        int d = nt * 16 + r16;
        float fb = (d < 60) ? fc2_b[d] : 0.f;
        acc2[nt] = (f32x4){fb, fb, fb, fb};
    }

    // F: GEMM1 half A (c 0..127) -> hb
#pragma unroll
    for (int nt = 0; nt < 8; ++nt) {
        const short* wr = pk + PK_W1 + (size_t)(nt * 16 + r16) * 72;
        bf16x8 w0 = *(const bf16x8*)(wr + g * 8);
        bf16x8 w1v = *(const bf16x8*)(wr + 32 + g * 8);
        int c = nt * 16 + r16;
        float fb = fc1_b[c];
        f32x4 acc = {fb, fb, fb, fb};
        acc = MFMA16(la0, w0, acc);
        acc = MFMA16(la1, w1v, acc);
#pragma unroll
        for (int r = 0; r < 4; ++r) {
            float u = acc[r];
            float zz = 1.5957691216057308f * u + 0.07135481178528657f * (u * u * u);
            float ge = u * __builtin_amdgcn_rcpf(1.f + __expf(-zz));
            R2[(m0 + g * 4 + r) * 136 + c] = f2b(ge);
        }
    }
    // G: GEMM2 pass 1 (K 0..127)
#pragma unroll
    for (int kk = 0; kk < 4; ++kk) {
        bf16x8 ha = *(const bf16x8*)&R2[(m0 + r16) * 136 + kk * 32 + g * 8];
#pragma unroll
        for (int nt = 0; nt < 4; ++nt) {
            const short* wr = pk + PK_W2 + (size_t)(nt * 16 + r16) * 264 + kk * 32 + g * 8;
            acc2[nt] = MFMA16(ha, *(const bf16x8*)wr, acc2[nt]);
        }
    }
    // zero hb cols 112..127 (own rows)
    *(int*)&R2[(m0 + r16) * 136 + 112 + g * 4]     = 0;
    *(int*)&R2[(m0 + r16) * 136 + 112 + g * 4 + 2] = 0;
    // H: GEMM1 half B (c 128..239) -> hb cols 0..111
#pragma unroll
    for (int nt = 0; nt < 7; ++nt) {
        const short* wr = pk + PK_W1 + (size_t)(128 + nt * 16 + r16) * 72;
        bf16x8 w0 = *(const bf16x8*)(wr + g * 8);
        bf16x8 w1v = *(const bf16x8*)(wr + 32 + g * 8);
        int c = nt * 16 + r16;
        float fb = fc1_b[128 + c];
        f32x4 acc = {fb, fb, fb, fb};
        acc = MFMA16(la0, w0, acc);
        acc = MFMA16(la1, w1v, acc);
#pragma unroll
        for (int r = 0; r < 4; ++r) {
            float u = acc[r];
            float zz = 1.5957691216057308f * u + 0.07135481178528657f * (u * u * u);
            float ge = u * __builtin_amdgcn_rcpf(1.f + __expf(-zz));
            R2[(m0 + g * 4 + r) * 136 + c] = f2b(ge);
        }
    }
    // I: GEMM2 pass 2 (K 128..255)
#pragma unroll
    for (int kk = 0; kk < 4; ++kk) {
        bf16x8 ha = *(const bf16x8*)&R2[(m0 + r16) * 136 + kk * 32 + g * 8];
#pragma unroll
        for (int nt = 0; nt < 4; ++nt) {
            const short* wr = pk + PK_W2 + (size_t)(nt * 16 + r16) * 264 + 128 + kk * 32 + g * 8;
            acc2[nt] = MFMA16(ha, *(const bf16x8*)wr, acc2[nt]);
        }
    }

    // ---- epilogue: v = y + mlp; stage (wave-local rows over hb), then coalesced store
#pragma unroll
    for (int nt = 0; nt < 4; ++nt) {
        int d = nt * 16 + r16;
        if (d < 60) {
#pragma unroll
            for (int r = 0; r < 4; ++r) {
                float yv = b2f((unsigned short)R1[(m0 + g * 4 + r) * 72 + d]);
                float v = yv + acc2[nt][r];
                if (L == 0) R2[(m0 + g * 4 + r) * 136 + d] = f2b(v);
                else        ((float*)R2)[(m0 + g * 4 + r) * 68 + d] = v;
            }
        }
    }
    __syncthreads();

    if (L == 0) {
        unsigned* ob = (unsigned*)xout_v;
        const size_t gbase = (size_t)b * NTOK * 30;
        for (int i = tid; i < 1920; i += 256) {
            int r = i / 30, c = i - r * 30;
            int gt = ((wy * 8 + (r >> 3)) << 6) + wx * 8 + (r & 7);
            ob[gbase + (size_t)gt * 30 + c] = *(unsigned*)&R2[r * 136 + 2 * c];
        }
    } else {
        float* of = (float*)xout_v;
        for (int i = tid; i < 3840; i += 256) {
            int d = i >> 6, t = i & 63;
            int gt = (((wy * 8 + (t >> 3) + 4) & 63) << 6) + ((wx * 8 + (t & 7) + 4) & 63);
            of[(size_t)d * NTOT + b * NTOK + gt] = ((const float*)R2)[t * 68 + d];
        }
    }
}

extern "C" void kernel_launch(void* const* d_in, const int* in_sizes, int n_in,
                              void* d_out, int out_size, void* d_ws, size_t ws_size,
                              hipStream_t stream)
{
    const float* x       = (const float*)d_in[0];
    const float* norm1_g = (const float*)d_in[1];
    const float* norm1_b = (const float*)d_in[2];
    const float* qkv_w   = (const float*)d_in[3];
    const float* qkv_b   = (const float*)d_in[4];
    const float* rpb     = (const float*)d_in[5];
    const float* proj_w  = (const float*)d_in[6];
    const float* proj_b  = (const float*)d_in[7];
    const float* norm2_g = (const float*)d_in[8];
    const float* norm2_b = (const float*)d_in[9];
    const float* fc1_w   = (const float*)d_in[10];
    const float* fc1_b   = (const float*)d_in[11];
    const float* fc2_w   = (const float*)d_in[12];
    const float* fc2_b   = (const float*)d_in[13];

    // ws: bufA bf16 (15.24MB) | pk (210KB) | btab fp32 (786KB)
    unsigned short* bufA = (unsigned short*)d_ws;
    short* pk  = (short*)((char*)d_ws + (size_t)NTOT * DIM * 2);
    float* btab = (float*)((char*)pk + 2 * PK_STRIDE * 2);

    dim3 block(256);
    pack_w<<<dim3(2, 8), block, 0, stream>>>(qkv_w, proj_w, fc1_w, fc2_w, rpb, pk, btab);

    dim3 grid(NB * 64);
    swin_layer<0><<<grid, block, 0, stream>>>(
        (const void*)x, (void*)bufA,
        norm1_g, norm1_b, norm2_g, norm2_b, pk, btab,
        qkv_b, proj_b, fc1_b, fc2_b);
    swin_layer<1><<<grid, block, 0, stream>>>(
        (const void*)bufA, d_out,
        norm1_g + 60, norm1_b + 60, norm2_g + 60, norm2_b + 60,
        pk + PK_STRIDE, btab + 4 * 24576,
        qkv_b + 180, proj_b + 60, fc1_b + 240, fc2_b + 60);

    (void)in_sizes; (void)n_in; (void)out_size; (void)ws_size;
}

// Round 6
// 176.397 us; speedup vs baseline: 22.6925x; 1.0104x over previous
//
#include <hip/hip_runtime.h>
#include <hip/hip_bf16.h>
#include <math.h>

// Swin stage: B=31, H=W=64, DIM=60, NH=6, HD=10, WS=8. One fused kernel/layer.
// Round 6: residual kept in registers (no 2nd activation read), chunked XCD
// swizzle for L2 line locality. LDS 29.4KB -> 5 blocks/CU.

#define NB 31
#define NTOK 4096
#define DIM 60
#define NTOT (NB*NTOK)
#define QK_SCALE 0.31622776601683794f

typedef __attribute__((ext_vector_type(8))) short bf16x8;
typedef __attribute__((ext_vector_type(4))) float f32x4;

__device__ __forceinline__ short f2b(float f){
    return __builtin_bit_cast(short, __float2bfloat16(f));
}
__device__ __forceinline__ float b2f(unsigned short u){
    union{unsigned u;float f;}v; v.u=((unsigned)u)<<16; return v.f;
}
__device__ __forceinline__ unsigned pk2(float a,float b){
    return (unsigned)(unsigned short)f2b(a) | ((unsigned)(unsigned short)f2b(b)<<16);
}
#define MFMA16(a,b,c) __builtin_amdgcn_mfma_f32_16x16x32_bf16(a,b,c,0,0,0)

// packed-weight offsets (shorts, per layer)
#define PK_QKV  0        // [192][72] head-grouped, q rows pre-scaled
#define PK_PROJ 13824    // [64][72]
#define PK_W1   18432    // [240][72]
#define PK_W2   35712    // [64][264]
#define PK_STRIDE 52608

// ---------------- pack: weights -> bf16, bias+mask -> fp32 table ----------------
__global__ __launch_bounds__(256) void pack_w(
    const float* __restrict__ qkv_w, const float* __restrict__ proj_w,
    const float* __restrict__ fc1_w, const float* __restrict__ fc2_w,
    const float* __restrict__ rpb, short* __restrict__ pk, float* __restrict__ btab)
{
    const int L = blockIdx.x;
    short* o = pk + (size_t)L * PK_STRIDE;
    const float* qw = qkv_w + L * 10800;
    const float* pw = proj_w + L * 3600;
    const float* w1 = fc1_w + L * 14400;
    const float* w2 = fc2_w + L * 14400;
    const float* rp = rpb + L * 1350;
    const int t0 = blockIdx.y * 256 + threadIdx.x;
    const int STP = 256 * 8;

    for (int i = t0; i < 192 * 72; i += STP) {
        int row = i / 72, k = i - row * 72;
        int p = row / 96, rg = row - p * 96;
        short v = 0;
        if (rg < 90 && k < 60) {
            int which = rg / 30, idx = rg - which * 30;
            int h = p * 3 + idx / 10, e = idx - (idx / 10) * 10;
            float wv = qw[(which * 60 + h * 10 + e) * 60 + k];
            if (which == 0) wv *= QK_SCALE;
            v = f2b(wv);
        }
        o[PK_QKV + i] = v;
    }
    for (int i = t0; i < 64 * 72; i += STP) {
        int n = i / 72, k = i - n * 72;
        o[PK_PROJ + i] = (n < 60 && k < 60) ? f2b(pw[n * 60 + k]) : (short)0;
    }
    for (int i = t0; i < 240 * 72; i += STP) {
        int n = i / 72, k = i - n * 72;
        o[PK_W1 + i] = (k < 60) ? f2b(w1[n * 60 + k]) : (short)0;
    }
    for (int i = t0; i < 64 * 264; i += STP) {
        int n = i / 264, k = i - n * 264;
        o[PK_W2 + i] = (n < 60 && k < 240) ? f2b(w2[n * 240 + k]) : (short)0;
    }
    // fp32 bias+mask table [L][cls][h][i][j]
    float* bo = btab + (size_t)L * 4 * 24576;
    for (int i = t0; i < 4 * 24576; i += STP) {
        int c = i / 24576, rem = i - c * 24576;
        int h = rem >> 12, rem2 = rem & 4095;
        int ii = rem2 >> 6, j = rem2 & 63;
        int iy = ii >> 3, ix = ii & 7, jy = j >> 3, jx = j & 7;
        float v = rp[((iy - jy + 7) * 15 + (ix - jx + 7)) * 6 + h];
        int riy = (c & 2) ? (iy < 4 ? 1 : 2) : 0;
        int rix = (c & 1) ? (ix < 4 ? 1 : 2) : 0;
        int rjy = (c & 2) ? (jy < 4 ? 1 : 2) : 0;
        int rjx = (c & 1) ? (jx < 4 ? 1 : 2) : 0;
        if (riy != rjy || rix != rjx) v -= 100.f;
        bo[i] = v;
    }
}

// ---------------- fused layer ----------------
// L=0: in fp32 (60,NTOT) d-major, shift 0, out bf16 (NTOT,60)
// L=1: in bf16 (NTOT,60), shift 4, out fp32 (60,NTOT)
template<int L>
__global__ __launch_bounds__(256, 5) void swin_layer(
    const void* __restrict__ xin_v, void* __restrict__ xout_v,
    const float* __restrict__ g1, const float* __restrict__ b1,
    const float* __restrict__ g2, const float* __restrict__ b2,
    const short* __restrict__ pk, const float* __restrict__ btab,
    const float* __restrict__ qkv_b, const float* __restrict__ proj_b,
    const float* __restrict__ fc1_b, const float* __restrict__ fc2_b)
{
    // R1: xn -> oac -> proj-out -> y  (stride 72, wave-local rows)
    // R2: qk[64][104]+vT[48][72] -> ln2/hb/sto (stride 136/68f, wave-local rows)
    __shared__ __attribute__((aligned(16))) short R1[64 * 72];    //  9216 B
    __shared__ __attribute__((aligned(16))) short R2[10112];      // 20224 B

    const f32x4 Z4 = {0.f, 0.f, 0.f, 0.f};
    const bf16x8 Z8 = {0, 0, 0, 0, 0, 0, 0, 0};

    const int tid = threadIdx.x;
    // chunked XCD swizzle: consecutive logical windows share an XCD's L2
    const int blk = ((blockIdx.x & 7) * 248) + (blockIdx.x >> 3);
    const int b = blk >> 6, w = blk & 63, wy = w >> 3, wx = w & 7;
    const int shift = L ? 4 : 0;
    const int cls = L ? (((wy == 7) ? 2 : 0) + ((wx == 7) ? 1 : 0)) : 0;

    const float* xf = (const float*)xin_v;
    const unsigned short* xb = (const unsigned short*)xin_v;

    // ---- A: zero Q/K e-pads + vT pad rows ----
    for (int i = tid; i < 64 * 18; i += 256) {
        int row = i / 18, t = i - row * 18, bc = t / 3, k = t - bc * 3;
        *(int*)&R2[row * 104 + bc * 16 + 10 + 2 * k] = 0;
    }
    for (int i = tid; i < 3 * 216; i += 256) {
        int hl = i / 216, j = i - hl * 216;
        *(int*)&R2[6656 + (hl * 16 + 10) * 72 + 2 * j] = 0;
    }

    // ---- LN1 -> R1; keep packed residual x in regs (xpk) ----
    const int tk = tid >> 2, l4 = tid & 3;
    const int tok = (((wy * 8 + (tk >> 3) + shift) & 63) << 6)
                  + ((wx * 8 + (tk & 7) + shift) & 63);
    unsigned xpk[8];
    if (L == 0) {
        float xr[15]; float s = 0.f, s2 = 0.f;
#pragma unroll
        for (int dd = 0; dd < 15; ++dd) {
            float v = xf[(size_t)(l4 * 15 + dd) * NTOT + b * NTOK + tok];
            xr[dd] = v; s += v; s2 += v * v;
        }
        s  += __shfl_xor(s, 1);  s  += __shfl_xor(s, 2);
        s2 += __shfl_xor(s2, 1); s2 += __shfl_xor(s2, 2);
        const float mu = s * (1.f / 60.f);
        const float rs = rsqrtf(s2 * (1.f / 60.f) - mu * mu + 1e-5f);
#pragma unroll
        for (int dd = 0; dd < 15; ++dd) {
            int d = l4 * 15 + dd;
            R1[tk * 72 + d] = f2b((xr[dd] - mu) * rs * g1[d] + b1[d]);
        }
#pragma unroll
        for (int u = 0; u < 3; ++u) R1[tk * 72 + 60 + l4 * 3 + u] = 0;
#pragma unroll
        for (int u = 0; u < 7; ++u) xpk[u] = pk2(xr[2 * u], xr[2 * u + 1]);
        xpk[7] = pk2(xr[14], 0.f);
    } else {
        float xr[16]; float s = 0.f, s2 = 0.f;
        const int nd = (l4 == 3) ? 6 : 8, c0 = l4 * 16;
        const unsigned* rp_ = (const unsigned*)(xb + ((size_t)b * NTOK + tok) * DIM) + l4 * 8;
#pragma unroll
        for (int j = 0; j < 8; ++j) {
            if (j < nd) {
                unsigned u = rp_[j];
                xpk[j] = u;
                float v0 = b2f((unsigned short)(u & 0xffff));
                float v1 = b2f((unsigned short)(u >> 16));
                xr[2 * j] = v0; xr[2 * j + 1] = v1;
                s += v0 + v1; s2 += v0 * v0 + v1 * v1;
            }
        }
        s  += __shfl_xor(s, 1);  s  += __shfl_xor(s, 2);
        s2 += __shfl_xor(s2, 1); s2 += __shfl_xor(s2, 2);
        const float mu = s * (1.f / 60.f);
        const float rs = rsqrtf(s2 * (1.f / 60.f) - mu * mu + 1e-5f);
#pragma unroll
        for (int j = 0; j < 8; ++j) {
            if (j < nd) {
                int d = c0 + 2 * j;
                float n0 = (xr[2 * j] - mu) * rs * g1[d] + b1[d];
                float n1 = (xr[2 * j + 1] - mu) * rs * g1[d + 1] + b1[d + 1];
                *(unsigned*)&R1[tk * 72 + d] = pk2(n0, n1);
            }
        }
        if (l4 == 3) {
#pragma unroll
            for (int u = 0; u < 3; ++u) *(unsigned*)&R1[tk * 72 + 60 + 2 * u] = 0;
        }
    }

    const int lane = tid & 63, r16 = lane & 15, g = lane >> 4;
    const int m0 = (tid >> 6) << 4;

    bf16x8 a0 = *(const bf16x8*)&R1[(m0 + r16) * 72 + g * 8];
    bf16x8 a1 = *(const bf16x8*)&R1[(m0 + r16) * 72 + 32 + g * 8];
    const float* btc = btab + (size_t)cls * 24576 + (m0 + r16) * 64;

    // ---- attention: two head-triples ----
    for (int p = 0; p < 2; ++p) {
#pragma unroll
        for (int nt = 0; nt < 6; ++nt) {
            const short* wr = pk + PK_QKV + (size_t)(p * 96 + nt * 16 + r16) * 72;
            bf16x8 w0 = *(const bf16x8*)(wr + g * 8);
            bf16x8 w1v = *(const bf16x8*)(wr + 32 + g * 8);
            int c = nt * 16 + r16;
            int which = 0, hl = 0, e = 0; float bias = 0.f;
            if (c < 90) {
                which = c / 30; int idx = c - which * 30;
                hl = idx / 10; e = idx - hl * 10;
                bias = qkv_b[which * 60 + (p * 3 + hl) * 10 + e];
                if (which == 0) bias *= QK_SCALE;
            }
            f32x4 acc = {bias, bias, bias, bias};
            acc = MFMA16(a0, w0, acc);
            acc = MFMA16(a1, w1v, acc);
            if (c < 90) {
                if (which == 0) {
#pragma unroll
                    for (int r = 0; r < 4; ++r)
                        R2[(m0 + g * 4 + r) * 104 + hl * 16 + e] = f2b(acc[r]);
                } else if (which == 1) {
#pragma unroll
                    for (int r = 0; r < 4; ++r)
                        R2[(m0 + g * 4 + r) * 104 + 48 + hl * 16 + e] = f2b(acc[r]);
                } else {
#pragma unroll
                    for (int r = 0; r < 2; ++r)
                        *(unsigned*)&R2[6656 + (hl * 16 + e) * 72 + m0 + g * 4 + 2 * r] =
                            pk2(acc[2 * r], acc[2 * r + 1]);
                }
            }
        }
        __syncthreads();

        for (int hl = 0; hl < 3; ++hl) {
            const int h = p * 3 + hl;
            bf16x8 qa = Z8;
            if (g < 2) qa = *(const bf16x8*)&R2[(m0 + r16) * 104 + hl * 16 + g * 8];
            const float* bh = btc + h * 4096;
            f32x4 sv[4];
#pragma unroll
            for (int nt = 0; nt < 4; ++nt) {
                bf16x8 kb = Z8;
                if (g < 2) kb = *(const bf16x8*)&R2[(nt * 16 + r16) * 104 + 48 + hl * 16 + g * 8];
                sv[nt] = MFMA16(kb, qa, *(const f32x4*)&bh[nt * 16 + g * 4]);
            }
            float mx = -1e30f;
#pragma unroll
            for (int nt = 0; nt < 4; ++nt)
#pragma unroll
                for (int r = 0; r < 4; ++r) mx = fmaxf(mx, sv[nt][r]);
            mx = fmaxf(mx, __shfl_xor(mx, 16));
            mx = fmaxf(mx, __shfl_xor(mx, 32));
            float sum = 0.f;
#pragma unroll
            for (int nt = 0; nt < 4; ++nt)
#pragma unroll
                for (int r = 0; r < 4; ++r) {
                    float e = __expf(sv[nt][r] - mx);
                    sv[nt][r] = e; sum += e;
                }
            sum += __shfl_xor(sum, 16);
            sum += __shfl_xor(sum, 32);
            const float inv = 1.f / sum;

            unsigned qd00 = pk2(sv[0][0], sv[0][1]), qd01 = pk2(sv[0][2], sv[0][3]);
            unsigned qd10 = pk2(sv[1][0], sv[1][1]), qd11 = pk2(sv[1][2], sv[1][3]);
            unsigned qd20 = pk2(sv[2][0], sv[2][1]), qd21 = pk2(sv[2][2], sv[2][3]);
            unsigned qd30 = pk2(sv[3][0], sv[3][1]), qd31 = pk2(sv[3][2], sv[3][3]);
            const int sA = (r16 + ((g & 1) << 5)) << 2;
            const int sB = sA + 64;
            const bool hi = (g >> 1) & 1;
            union { unsigned u[4]; bf16x8 v; } pb0, pb1;
            {
                unsigned x0 = __builtin_amdgcn_ds_bpermute(sA, (int)qd00);
                unsigned y0 = __builtin_amdgcn_ds_bpermute(sA, (int)qd10);
                pb0.u[0] = hi ? y0 : x0;
                unsigned x1 = __builtin_amdgcn_ds_bpermute(sA, (int)qd01);
                unsigned y1 = __builtin_amdgcn_ds_bpermute(sA, (int)qd11);
                pb0.u[1] = hi ? y1 : x1;
                unsigned x2 = __builtin_amdgcn_ds_bpermute(sB, (int)qd00);
                unsigned y2 = __builtin_amdgcn_ds_bpermute(sB, (int)qd10);
                pb0.u[2] = hi ? y2 : x2;
                unsigned x3 = __builtin_amdgcn_ds_bpermute(sB, (int)qd01);
                unsigned y3 = __builtin_amdgcn_ds_bpermute(sB, (int)qd11);
                pb0.u[3] = hi ? y3 : x3;
                unsigned u0 = __builtin_amdgcn_ds_bpermute(sA, (int)qd20);
                unsigned v0 = __builtin_amdgcn_ds_bpermute(sA, (int)qd30);
                pb1.u[0] = hi ? v0 : u0;
                unsigned u1 = __builtin_amdgcn_ds_bpermute(sA, (int)qd21);
                unsigned v1 = __builtin_amdgcn_ds_bpermute(sA, (int)qd31);
                pb1.u[1] = hi ? v1 : u1;
                unsigned u2 = __builtin_amdgcn_ds_bpermute(sB, (int)qd20);
                unsigned v2 = __builtin_amdgcn_ds_bpermute(sB, (int)qd30);
                pb1.u[2] = hi ? v2 : u2;
                unsigned u3 = __builtin_amdgcn_ds_bpermute(sB, (int)qd21);
                unsigned v3 = __builtin_amdgcn_ds_bpermute(sB, (int)qd31);
                pb1.u[3] = hi ? v3 : u3;
            }
            bf16x8 va0 = *(const bf16x8*)&R2[6656 + (hl * 16 + r16) * 72 + g * 8];
            bf16x8 va1 = *(const bf16x8*)&R2[6656 + (hl * 16 + r16) * 72 + 32 + g * 8];
            f32x4 o = MFMA16(va0, pb0.v, Z4);
            o = MFMA16(va1, pb1.v, o);
            if (g < 2) {
                *(unsigned*)&R1[(m0 + r16) * 72 + h * 10 + g * 4]     = pk2(o[0] * inv, o[1] * inv);
                *(unsigned*)&R1[(m0 + r16) * 72 + h * 10 + g * 4 + 2] = pk2(o[2] * inv, o[3] * inv);
            } else if (g == 2) {
                *(unsigned*)&R1[(m0 + r16) * 72 + h * 10 + 8] = pk2(o[0] * inv, o[1] * inv);
            }
        }
        __syncthreads();
    }

    // ---- D: proj (+bias) -> R1 rows (no residual here) ----
    {
        bf16x8 oa0 = *(const bf16x8*)&R1[(m0 + r16) * 72 + g * 8];
        bf16x8 oa1 = *(const bf16x8*)&R1[(m0 + r16) * 72 + 32 + g * 8];
#pragma unroll
        for (int nt = 0; nt < 4; ++nt) {
            const short* wr = pk + PK_PROJ + (size_t)(nt * 16 + r16) * 72;
            bf16x8 w0 = *(const bf16x8*)(wr + g * 8);
            bf16x8 w1v = *(const bf16x8*)(wr + 32 + g * 8);
            int d = nt * 16 + r16;
            float pb_ = (d < 60) ? proj_b[d] : 0.f;
            f32x4 acc = {pb_, pb_, pb_, pb_};
            acc = MFMA16(oa0, w0, acc);
            acc = MFMA16(oa1, w1v, acc);
            if (d < 60) {
#pragma unroll
                for (int r = 0; r < 4; ++r)
                    R1[(m0 + g * 4 + r) * 72 + d] = f2b(acc[r]);
            }
        }
    }

    // ---- E: residual (from xpk regs) + LN2; y -> R1, ln2 -> R2 ----
    if (L == 0) {
        float yv[15]; float s = 0.f, s2 = 0.f;
#pragma unroll
        for (int dd = 0; dd < 15; ++dd) {
            int d = l4 * 15 + dd;
            float xv = b2f((unsigned short)((dd & 1) ? (xpk[dd >> 1] >> 16)
                                                    : (xpk[dd >> 1] & 0xffff)));
            float y = xv + b2f((unsigned short)R1[tk * 72 + d]);
            yv[dd] = y; s += y; s2 += y * y;
        }
        s  += __shfl_xor(s, 1);  s  += __shfl_xor(s, 2);
        s2 += __shfl_xor(s2, 1); s2 += __shfl_xor(s2, 2);
        const float mu = s * (1.f / 60.f);
        const float rs = rsqrtf(s2 * (1.f / 60.f) - mu * mu + 1e-5f);
#pragma unroll
        for (int dd = 0; dd < 15; ++dd) {
            int d = l4 * 15 + dd;
            R1[tk * 72 + d] = f2b(yv[dd]);
            R2[tk * 136 + d] = f2b((yv[dd] - mu) * rs * g2[d] + b2[d]);
        }
#pragma unroll
        for (int u = 0; u < 3; ++u) R2[tk * 136 + 60 + l4 * 3 + u] = 0;
    } else {
        float yv[16]; float s = 0.f, s2 = 0.f;
        const int nd = (l4 == 3) ? 6 : 8, c0 = l4 * 16;
#pragma unroll
        for (int j = 0; j < 8; ++j) {
            if (j < nd) {
                int d = c0 + 2 * j;
                float y0 = b2f((unsigned short)(xpk[j] & 0xffff))
                         + b2f((unsigned short)R1[tk * 72 + d]);
                float y1 = b2f((unsigned short)(xpk[j] >> 16))
                         + b2f((unsigned short)R1[tk * 72 + d + 1]);
                yv[2 * j] = y0; yv[2 * j + 1] = y1;
                s += y0 + y1; s2 += y0 * y0 + y1 * y1;
            }
        }
        s  += __shfl_xor(s, 1);  s  += __shfl_xor(s, 2);
        s2 += __shfl_xor(s2, 1); s2 += __shfl_xor(s2, 2);
        const float mu = s * (1.f / 60.f);
        const float rs = rsqrtf(s2 * (1.f / 60.f) - mu * mu + 1e-5f);
#pragma unroll
        for (int j = 0; j < 8; ++j) {
            if (j < nd) {
                int d = c0 + 2 * j;
                *(unsigned*)&R1[tk * 72 + d] = pk2(yv[2 * j], yv[2 * j + 1]);
                float n0 = (yv[2 * j] - mu) * rs * g2[d] + b2[d];
                float n1 = (yv[2 * j + 1] - mu) * rs * g2[d + 1] + b2[d + 1];
                *(unsigned*)&R2[tk * 136 + d] = pk2(n0, n1);
            }
        }
        if (l4 == 3) {
#pragma unroll
            for (int u = 0; u < 3; ++u) *(unsigned*)&R2[tk * 136 + 60 + 2 * u] = 0;
        }
    }

    bf16x8 la0 = *(const bf16x8*)&R2[(m0 + r16) * 136 + g * 8];
    bf16x8 la1 = *(const bf16x8*)&R2[(m0 + r16) * 136 + 32 + g * 8];

    f32x4 acc2[4];
#pragma unroll
    for (int nt = 0; nt < 4; ++nt) {
        int d = nt * 16 + r16;
        float fb = (d < 60) ? fc2_b[d] : 0.f;
        acc2[nt] = (f32x4){fb, fb, fb, fb};
    }

    // F: GEMM1 half A (c 0..127) -> hb
#pragma unroll
    for (int nt = 0; nt < 8; ++nt) {
        const short* wr = pk + PK_W1 + (size_t)(nt * 16 + r16) * 72;
        bf16x8 w0 = *(const bf16x8*)(wr + g * 8);
        bf16x8 w1v = *(const bf16x8*)(wr + 32 + g * 8);
        int c = nt * 16 + r16;
        float fb = fc1_b[c];
        f32x4 acc = {fb, fb, fb, fb};
        acc = MFMA16(la0, w0, acc);
        acc = MFMA16(la1, w1v, acc);
#pragma unroll
        for (int r = 0; r < 4; ++r) {
            float u = acc[r];
            float zz = 1.5957691216057308f * u + 0.07135481178528657f * (u * u * u);
            float ge = u * __builtin_amdgcn_rcpf(1.f + __expf(-zz));
            R2[(m0 + g * 4 + r) * 136 + c] = f2b(ge);
        }
    }
    // G: GEMM2 pass 1 (K 0..127)
#pragma unroll
    for (int kk = 0; kk < 4; ++kk) {
        bf16x8 ha = *(const bf16x8*)&R2[(m0 + r16) * 136 + kk * 32 + g * 8];
#pragma unroll
        for (int nt = 0; nt < 4; ++nt) {
            const short* wr = pk + PK_W2 + (size_t)(nt * 16 + r16) * 264 + kk * 32 + g * 8;
            acc2[nt] = MFMA16(ha, *(const bf16x8*)wr, acc2[nt]);
        }
    }
    // zero hb cols 112..127 (own rows)
    *(int*)&R2[(m0 + r16) * 136 + 112 + g * 4]     = 0;
    *(int*)&R2[(m0 + r16) * 136 + 112 + g * 4 + 2] = 0;
    // H: GEMM1 half B (c 128..239) -> hb cols 0..111
#pragma unroll
    for (int nt = 0; nt < 7; ++nt) {
        const short* wr = pk + PK_W1 + (size_t)(128 + nt * 16 + r16) * 72;
        bf16x8 w0 = *(const bf16x8*)(wr + g * 8);
        bf16x8 w1v = *(const bf16x8*)(wr + 32 + g * 8);
        int c = nt * 16 + r16;
        float fb = fc1_b[128 + c];
        f32x4 acc = {fb, fb, fb, fb};
        acc = MFMA16(la0, w0, acc);
        acc = MFMA16(la1, w1v, acc);
#pragma unroll
        for (int r = 0; r < 4; ++r) {
            float u = acc[r];
            float zz = 1.5957691216057308f * u + 0.07135481178528657f * (u * u * u);
            float ge = u * __builtin_amdgcn_rcpf(1.f + __expf(-zz));
            R2[(m0 + g * 4 + r) * 136 + c] = f2b(ge);
        }
    }
    // I: GEMM2 pass 2 (K 128..255)
#pragma unroll
    for (int kk = 0; kk < 4; ++kk) {
        bf16x8 ha = *(const bf16x8*)&R2[(m0 + r16) * 136 + kk * 32 + g * 8];
#pragma unroll
        for (int nt = 0; nt < 4; ++nt) {
            const short* wr = pk + PK_W2 + (size_t)(nt * 16 + r16) * 264 + 128 + kk * 32 + g * 8;
            acc2[nt] = MFMA16(ha, *(const bf16x8*)wr, acc2[nt]);
        }
    }

    // ---- epilogue: v = y + mlp; stage, then coalesced store ----
#pragma unroll
    for (int nt = 0; nt < 4; ++nt) {
        int d = nt * 16 + r16;
        if (d < 60) {
#pragma unroll
            for (int r = 0; r < 4; ++r) {
                float yv = b2f((unsigned short)R1[(m0 + g * 4 + r) * 72 + d]);
                float v = yv + acc2[nt][r];
                if (L == 0) R2[(m0 + g * 4 + r) * 136 + d] = f2b(v);
                else        ((float*)R2)[(m0 + g * 4 + r) * 68 + d] = v;
            }
        }
    }
    __syncthreads();

    if (L == 0) {
        unsigned* ob = (unsigned*)xout_v;
        const size_t gbase = (size_t)b * NTOK * 30;
        for (int i = tid; i < 1920; i += 256) {
            int r = i / 30, c = i - r * 30;
            int gt = ((wy * 8 + (r >> 3)) << 6) + wx * 8 + (r & 7);
            ob[gbase + (size_t)gt * 30 + c] = *(unsigned*)&R2[r * 136 + 2 * c];
        }
    } else {
        float* of = (float*)xout_v;
        for (int i = tid; i < 3840; i += 256) {
            int d = i >> 6, t = i & 63;
            int gt = (((wy * 8 + (t >> 3) + 4) & 63) << 6) + ((wx * 8 + (t & 7) + 4) & 63);
            of[(size_t)d * NTOT + b * NTOK + gt] = ((const float*)R2)[t * 68 + d];
        }
    }
}

extern "C" void kernel_launch(void* const* d_in, const int* in_sizes, int n_in,
                              void* d_out, int out_size, void* d_ws, size_t ws_size,
                              hipStream_t stream)
{
    const float* x       = (const float*)d_in[0];
    const float* norm1_g = (const float*)d_in[1];
    const float* norm1_b = (const float*)d_in[2];
    const float* qkv_w   = (const float*)d_in[3];
    const float* qkv_b   = (const float*)d_in[4];
    const float* rpb     = (const float*)d_in[5];
    const float* proj_w  = (const float*)d_in[6];
    const float* proj_b  = (const float*)d_in[7];
    const float* norm2_g = (const float*)d_in[8];
    const float* norm2_b = (const float*)d_in[9];
    const float* fc1_w   = (const float*)d_in[10];
    const float* fc1_b   = (const float*)d_in[11];
    const float* fc2_w   = (const float*)d_in[12];
    const float* fc2_b   = (const float*)d_in[13];

    unsigned short* bufA = (unsigned short*)d_ws;
    short* pk  = (short*)((char*)d_ws + (size_t)NTOT * DIM * 2);
    float* btab = (float*)((char*)pk + 2 * PK_STRIDE * 2);

    dim3 block(256);
    pack_w<<<dim3(2, 8), block, 0, stream>>>(qkv_w, proj_w, fc1_w, fc2_w, rpb, pk, btab);

    dim3 grid(NB * 64);
    swin_layer<0><<<grid, block, 0, stream>>>(
        (const void*)x, (void*)bufA,
        norm1_g, norm1_b, norm2_g, norm2_b, pk, btab,
        qkv_b, proj_b, fc1_b, fc2_b);
    swin_layer<1><<<grid, block, 0, stream>>>(
        (const void*)bufA, d_out,
        norm1_g + 60, norm1_b + 60, norm2_g + 60, norm2_b + 60,
        pk + PK_STRIDE, btab + 4 * 24576,
        qkv_b + 180, proj_b + 60, fc1_b + 240, fc2_b + 60);

    (void)in_sizes; (void)n_in; (void)out_size; (void)ws_size;
}